// Round 1
// 334.438 us; speedup vs baseline: 1.1377x; 1.1377x over previous
//
#include <hip/hip_runtime.h>

// FADE-Lite round 8: restructure o4_kernels (the 88us latency-bound straggler).
// Old o4: 256 blocks (1 per CU), 450 serial loads/thread, raw[25] spilled to
// scratch (VGPR_Count=20 < 25). New o4: 1024 blocks, 4 tap-groups x 64 pixels,
// ~120 loads/thread, LDS tile for raw values, softmax re-reads LDS (no register
// array, no spill). Everything else identical to the verified round-7 kernel.
//
// out = gate*en + (1-gate)*CARAFE(de, softmax_k(dw3x3(conv1x1(en,Wce))+up2(dw3x3(conv1x1(de,Wcd)))))
// B=4, C=256, H=64, W=64. Inputs fp32 (runtime-detected), output fp32.

typedef unsigned short u16;
typedef unsigned int u32;

#define NB 4
#define NC 256
#define NH 64
#define NW 64
#define NH2 128
#define NW2 128

// fp32 weights in ws (shared by both paths)
#define OFF_WG   0
#define OFF_BG   256
#define OFF_WCE  272
#define OFF_BCE  6672
#define OFF_WCD  6704
#define OFF_WDW  13104
#define OFF_BDW  13330
#define OFF_FLAG 13356    // 1.0f = fp32 inputs, 0.0f = bf16 inputs

// ---- optimized (full-batch) layout, floats ----
#define OFF_GATE 16384    // 4*4096 fp32                    -> 32768
#define OFF_KB   32768    // 4*4096*100 u16 (819200 fl)     -> 851968
#define OFF_ENC  851968   // 4*25*16384 fp32                -> 2490368
#define OFF_DEC  2490368  // 4*25*4096 fp32                 -> 2899968
#define OFF_DET  851968   // 4*68*68*256 u16, aliases dead ENC+DEC after o4 -> 3219456
#define FULL_NEED_BYTES 12877824ull

// ---- naive (per-batch) layout, floats ----
#define NGATE 16384
#define NDEC  20480
#define NENC  122880
#define NKBF  532480      // -> end 942080 (3.77 MB)

__device__ __forceinline__ float bf2f(u16 u){ return __uint_as_float(((u32)u) << 16); }
__device__ __forceinline__ u16 f2bf(float f){
  u32 x = __float_as_uint(f);
  return (u16)((x + 0x7fffu + ((x >> 16) & 1u)) >> 16);  // RNE (finite)
}
__device__ __forceinline__ float ldin(const void* p, int i, bool f32){
  return f32 ? ((const float*)p)[i] : bf2f(((const u16*)p)[i]);
}

// dtype detector on `de` (~N(0,1)): bf16 exp in [0x70,0x82] nearly always;
// fp32 low-mantissa u16s ~uniform (~7% hit).
__global__ __launch_bounds__(256) void k_detect(const void* de_raw, float* ws){
  __shared__ int cnt;
  if (threadIdx.x == 0) cnt = 0;
  __syncthreads();
  int c = 0;
#pragma unroll
  for (int s = 0; s < 2; s++) {
    int i = (threadIdx.x + s * 256) * 2;
    u16 u = ((const u16*)de_raw)[i];
    int e = (u >> 7) & 0xff;
    if (e >= 0x70 && e <= 0x82) c++;
  }
  atomicAdd(&cnt, c);
  __syncthreads();
  if (threadIdx.x == 0) ws[OFF_FLAG] = (cnt < 256) ? 1.0f : 0.0f;
}

__global__ __launch_bounds__(256) void k_prep(const void* Wg, const void* bg,
    const void* Wce, const void* bce, const void* Wcd, const void* Wdw, const void* bdw,
    float* ws){
  bool f = ws[OFF_FLAG] != 0.f;
  int i = threadIdx.x + blockIdx.x * 256;
  if (i < 6400) {
    ws[OFF_WCE + i] = ldin(Wce, i, f);
    ws[OFF_WCD + i] = ldin(Wcd, i, f);
    if (i < 256) ws[OFF_WG + i] = ldin(Wg, i, f);
    if (i < 1)   ws[OFF_BG + i] = ldin(bg, i, f);
    if (i < 25)  ws[OFF_BCE + i] = ldin(bce, i, f);
    if (i < 225) ws[OFF_WDW + i] = ldin(Wdw, i, f);
    if (i < 25)  ws[OFF_BDW + i] = ldin(bdw, i, f);
  }
}

// ================= optimized path =================

// DEC = conv1x1(de, W_cd); GATE = sigmoid(conv1x1(de,W_gate)+b_gate)
// grid = B*H (256), block 256 = 4 c-groups x 64 w
__global__ __launch_bounds__(256) void o1_dec_gate(const void* de, float* ws){
  __shared__ float red[4][26][64];
  bool f = ws[OFF_FLAG] != 0.f;
  int b = blockIdx.x >> 6;
  int h = blockIdx.x & 63;
  int g = threadIdx.x >> 6;
  int w = threadIdx.x & 63;
  int c0 = __builtin_amdgcn_readfirstlane(g * 64);
  float acc[26];
#pragma unroll
  for (int o = 0; o < 26; o++) acc[o] = 0.f;
  int idx = ((b * NC + c0) * NH + h) * NW + w;
  for (int ci = 0; ci < 64; ci++) {
    float v = ldin(de, idx, f); idx += NH * NW;
    int c = c0 + ci;
    acc[25] += ws[OFF_WG + c] * v;
#pragma unroll
    for (int k = 0; k < 25; k++) acc[k] += ws[OFF_WCD + k * 256 + c] * v;
  }
#pragma unroll
  for (int o = 0; o < 26; o++) red[g][o][w] = acc[o];
  __syncthreads();
  for (int item = threadIdx.x; item < 26 * 64; item += 256) {
    int o = item >> 6; int ww = item & 63;
    float s = red[0][o][ww] + red[1][o][ww] + red[2][o][ww] + red[3][o][ww];
    if (o < 25) ws[OFF_DEC + ((b * 25 + o) * NH + h) * NW + ww] = s;
    else {
      float z = s + ws[OFF_BG];
      ws[OFF_GATE + (b * NH + h) * NW + ww] = 1.f / (1.f + __expf(-z));
    }
  }
}

// DET[b][p][q][c] = de[b][c][p-2][q-2] (0 outside), bf16. Runs AFTER o4 (aliases ENC+DEC).
// grid = B*68, block 256 (=c)
__global__ __launch_bounds__(256) void o2_det(const void* de, float* ws){
  bool f = ws[OFF_FLAG] != 0.f;
  u16* det = (u16*)(ws + OFF_DET);
  int b = blockIdx.x / 68;
  int p = blockIdx.x % 68;
  int c = threadIdx.x;
  int h = p - 2;
  bool hv = (h >= 0 && h < NH);
  int sbase = ((b * NC + c) * NH + (hv ? h : 0)) * NW;
  u16* dst = det + ((b * 68 + p) * 68) * NC + c;
  for (int q = 0; q < 68; q++) {
    int w = q - 2;
    float v = (hv && w >= 0 && w < NW) ? ldin(de, sbase + w, f) : 0.f;
    dst[q * NC] = f2bf(v);
  }
}

// ENC = conv1x1(en, W_ce)+b_ce.  grid = B*128 (512), block 256 = 2 c-groups x 128 x
__global__ __launch_bounds__(256) void o3_enc(const void* en, float* ws){
  __shared__ float red[2][25][128];
  bool f = ws[OFF_FLAG] != 0.f;
  int b = blockIdx.x >> 7;
  int y = blockIdx.x & 127;
  int g = threadIdx.x >> 7;
  int x = threadIdx.x & 127;
  int c0 = __builtin_amdgcn_readfirstlane(g * 128);
  float acc[25];
#pragma unroll
  for (int k = 0; k < 25; k++) acc[k] = 0.f;
  int idx = ((b * NC + c0) * NH2 + y) * NW2 + x;
  for (int ci = 0; ci < 128; ci++) {
    float v = ldin(en, idx, f); idx += NH2 * NW2;
    int c = c0 + ci;
#pragma unroll
    for (int k = 0; k < 25; k++) acc[k] += ws[OFF_WCE + k * 256 + c] * v;
  }
#pragma unroll
  for (int k = 0; k < 25; k++) red[g][k][x] = acc[k];
  __syncthreads();
  for (int item = threadIdx.x; item < 25 * 128; item += 256) {
    int k = item >> 7; int xx = item & 127;
    float s = red[0][k][xx] + red[1][k][xx] + ws[OFF_BCE + k];
    ws[OFF_ENC + ((b * 25 + k) * NH2 + y) * NW2 + xx] = s;
  }
}

// raw = dw3x3(ENC)+b + up2(dw3x3(DEC)+b); softmax over 25 -> KB bf16 [b][h][w][tap*4+st]
// grid = B*128*2 (1024): each block = one output row y, 64-pixel x-strip.
// 256 threads = 4 tap-groups x 64 pixels; group tg computes taps k=tg,tg+4,...
// Partial raw values go to LDS red[25][64]; wave 0 does softmax straight from
// LDS (no 25-register array -> no scratch spill, which killed the old version).
__global__ __launch_bounds__(256) void o4_kernels(float* ws){
  __shared__ float red[25][64];
  int b = blockIdx.x >> 8;
  int rem = blockIdx.x & 255;
  int y = rem >> 1;
  int xs = (rem & 1) << 6;
  int tg = __builtin_amdgcn_readfirstlane(threadIdx.x >> 6);
  int xl = threadIdx.x & 63;
  int x = xs + xl;
  int h = y >> 1, w = x >> 1;
  const float* enc = ws + OFF_ENC + (b * 25) * NH2 * NW2;
  const float* dec = ws + OFF_DEC + (b * 25) * NH * NW;

  for (int k = tg; k < 25; k += 4) {
    float s = 2.f * ws[OFF_BDW + k];
#pragma unroll
    for (int u = 0; u < 3; u++) {
      int yy = y + u - 1, hh = h + u - 1;
      bool yok = (yy >= 0 && yy < NH2);
      bool hok = (hh >= 0 && hh < NH);
#pragma unroll
      for (int v = 0; v < 3; v++) {
        int xx = x + v - 1, w2 = w + v - 1;
        float wd = ws[OFF_WDW + k * 9 + u * 3 + v];
        if (yok && xx >= 0 && xx < NW2)
          s += enc[(k * NH2 + yy) * NW2 + xx] * wd;
        if (hok && w2 >= 0 && w2 < NW)
          s += dec[(k * NH + hh) * NW + w2] * wd;
      }
    }
    red[k][xl] = s;
  }
  __syncthreads();

  if (threadIdx.x < 64) {
    int t = threadIdx.x;
    int xp = xs + t;
    float m = -1e30f;
#pragma unroll
    for (int k = 0; k < 25; k++) m = fmaxf(m, red[k][t]);
    float sum = 0.f;
#pragma unroll
    for (int k = 0; k < 25; k++) {
      float e = __expf(red[k][t] - m);
      red[k][t] = e;
      sum += e;
    }
    float inv = 1.f / sum;
    int st = ((y & 1) << 1) + (xp & 1);
    int wp = xp >> 1;
    u16* kbu = (u16*)(ws + OFF_KB);
    u16* dst = kbu + ((b * NH + h) * NW + wp) * 100 + st;
#pragma unroll
    for (int k = 0; k < 25; k++) dst[k * 4] = f2bf(red[k][t] * inv);
  }
}

// Channel-major carafe + gate blend, fp32 out. grid = B*64*4 (1024), block 256 (4 waves).
__global__ __launch_bounds__(256) void o5_final(const void* en, float* ws, float* out){
  __shared__ u16 stag[2][32][260];
  bool f = ws[OFF_FLAG] != 0.f;
  const u16* det = (const u16*)(ws + OFF_DET);
  const u16* kbu = (const u16*)(ws + OFF_KB);
  const float* gate = ws + OFF_GATE;

  int b = blockIdx.x >> 8;
  int rem = blockIdx.x & 255;
  int h = rem >> 2;
  int w0b = (rem & 3) * 16;
  int wave = threadIdx.x >> 6;
  int lane = threadIdx.x & 63;
  int c4 = lane * 4;

  for (int i = 0; i < 4; i++) {
    int wu = __builtin_amdgcn_readfirstlane(w0b + wave * 4 + i);
    const u16* kp = kbu + ((b * NH + h) * NW + wu) * 100;
    float acc[4][4];
#pragma unroll
    for (int st = 0; st < 4; st++)
#pragma unroll
      for (int j = 0; j < 4; j++) acc[st][j] = 0.f;

#pragma unroll
    for (int dy = 0; dy < 5; dy++) {
      const u16* dp = det + (((b * 68 + h + dy) * 68 + wu) * NC) + c4;
#pragma unroll
      for (int dx = 0; dx < 5; dx++) {
        ushort4 uv = *(const ushort4*)(dp + dx * NC);
        float v0 = bf2f(uv.x), v1 = bf2f(uv.y), v2 = bf2f(uv.z), v3 = bf2f(uv.w);
        const u32* kpu = (const u32*)(kp + (dy * 5 + dx) * 4);
        u32 k01 = kpu[0], k23 = kpu[1];
        float k0 = bf2f((u16)(k01 & 0xffffu));
        float k1 = bf2f((u16)(k01 >> 16));
        float k2 = bf2f((u16)(k23 & 0xffffu));
        float k3 = bf2f((u16)(k23 >> 16));
        acc[0][0] += k0 * v0; acc[0][1] += k0 * v1; acc[0][2] += k0 * v2; acc[0][3] += k0 * v3;
        acc[1][0] += k1 * v0; acc[1][1] += k1 * v1; acc[1][2] += k1 * v2; acc[1][3] += k1 * v3;
        acc[2][0] += k2 * v0; acc[2][1] += k2 * v1; acc[2][2] += k2 * v2; acc[2][3] += k2 * v3;
        acc[3][0] += k3 * v0; acc[3][1] += k3 * v1; acc[3][2] += k3 * v2; acc[3][3] += k3 * v3;
      }
    }
    int xl = (wave * 4 + i) * 2;
#pragma unroll
    for (int s = 0; s < 2; s++)
#pragma unroll
      for (int t = 0; t < 2; t++) {
        int st = s * 2 + t;
        ushort4 pv;
        pv.x = f2bf(acc[st][0]); pv.y = f2bf(acc[st][1]);
        pv.z = f2bf(acc[st][2]); pv.w = f2bf(acc[st][3]);
        *(ushort4*)&stag[s][xl + t][c4] = pv;
      }
  }
  __syncthreads();

  int xp = threadIdx.x & 31;
  int cb = (threadIdx.x >> 5) * 2;
  int x = w0b * 2 + xp;
  int wpix = w0b + (xp >> 1);
  float g = gate[(b * NH + h) * NW + wpix];
  float gi = 1.f - g;
#pragma unroll
  for (int pass = 0; pass < 16; pass++) {
    int c = cb + pass * 16;
#pragma unroll
    for (int s = 0; s < 2; s++) {
      int y = 2 * h + s;
      u32 rr = *(const u32*)&stag[s][xp][c];
      float cr0 = bf2f((u16)(rr & 0xffffu));
      float cr1 = bf2f((u16)(rr >> 16));
      int eidx = ((b * NC + c) * NH2 + y) * NW2 + x;
      float e0 = ldin(en, eidx, f);
      float e1 = ldin(en, eidx + NH2 * NW2, f);
      out[eidx] = g * e0 + gi * cr0;
      out[eidx + NH2 * NW2] = g * e1 + gi * cr1;
    }
  }
}

// ================= naive fallback path (verified round 6) =================

__global__ __launch_bounds__(256) void kA_gate(const void* de, float* ws, int b){
  bool f = ws[OFF_FLAG] != 0.f;
  int idx = blockIdx.x * 256 + threadIdx.x;
  int h = idx >> 6, w = idx & 63;
  float s = ws[OFF_BG];
  for (int c = 0; c < NC; c++)
    s += ldin(de, ((b * NC + c) * NH + h) * NW + w, f) * ws[OFF_WG + c];
  ws[NGATE + idx] = 1.f / (1.f + __expf(-s));
}

__global__ __launch_bounds__(256) void kB_dec(const void* de, float* ws, int b){
  bool f = ws[OFF_FLAG] != 0.f;
  int idx = blockIdx.x * 256 + threadIdx.x;
  int h = idx >> 6, w = idx & 63;
  float acc[25];
#pragma unroll
  for (int k = 0; k < 25; k++) acc[k] = 0.f;
  for (int c = 0; c < NC; c++) {
    float v = ldin(de, ((b * NC + c) * NH + h) * NW + w, f);
#pragma unroll
    for (int k = 0; k < 25; k++) acc[k] += v * ws[OFF_WCD + k * 256 + c];
  }
#pragma unroll
  for (int k = 0; k < 25; k++)
    ws[NDEC + (k * NH + h) * NW + w] = acc[k];
}

__global__ __launch_bounds__(256) void kC_enc(const void* en, float* ws, int b){
  bool f = ws[OFF_FLAG] != 0.f;
  int idx = blockIdx.x * 256 + threadIdx.x;
  int y = idx >> 7, x = idx & 127;
  float acc[25];
#pragma unroll
  for (int k = 0; k < 25; k++) acc[k] = 0.f;
  for (int c = 0; c < NC; c++) {
    float v = ldin(en, ((b * NC + c) * NH2 + y) * NW2 + x, f);
#pragma unroll
    for (int k = 0; k < 25; k++) acc[k] += v * ws[OFF_WCE + k * 256 + c];
  }
#pragma unroll
  for (int k = 0; k < 25; k++)
    ws[NENC + (k * NH2 + y) * NW2 + x] = acc[k] + ws[OFF_BCE + k];
}

__global__ __launch_bounds__(256) void kD_kern(float* ws){
  int idx = blockIdx.x * 256 + threadIdx.x;
  int y = idx >> 7, x = idx & 127;
  int h = y >> 1, w = x >> 1;
  float raw[25];
#pragma unroll
  for (int k = 0; k < 25; k++) {
    float s = 2.f * ws[OFF_BDW + k];
#pragma unroll
    for (int u = 0; u < 3; u++) {
      int yy = y + u - 1, hh = h + u - 1;
#pragma unroll
      for (int v = 0; v < 3; v++) {
        int xx = x + v - 1, ww = w + v - 1;
        float wd = ws[OFF_WDW + k * 9 + u * 3 + v];
        if (yy >= 0 && yy < NH2 && xx >= 0 && xx < NW2)
          s += ws[NENC + (k * NH2 + yy) * NW2 + xx] * wd;
        if (hh >= 0 && hh < NH && ww >= 0 && ww < NW)
          s += ws[NDEC + (k * NH + hh) * NW + ww] * wd;
      }
    }
    raw[k] = s;
  }
  float m = raw[0];
#pragma unroll
  for (int k = 1; k < 25; k++) m = fmaxf(m, raw[k]);
  float sum = 0.f;
#pragma unroll
  for (int k = 0; k < 25; k++) { raw[k] = __expf(raw[k] - m); sum += raw[k]; }
  float inv = 1.f / sum;
  float* dst = ws + NKBF + idx * 25;
#pragma unroll
  for (int k = 0; k < 25; k++) dst[k] = raw[k] * inv;
}

__global__ __launch_bounds__(256) void kE_out(const void* en, const void* de,
    const float* ws, float* out, int b){
  bool f = ws[OFF_FLAG] != 0.f;
  int idx = blockIdx.x * 256 + threadIdx.x;
  int c = idx >> 14;
  int y = (idx >> 7) & 127;
  int x = idx & 127;
  int h = y >> 1, w = x >> 1;
  const float* kb = ws + NKBF + (y * NW2 + x) * 25;
  float acc = 0.f;
#pragma unroll
  for (int dy = 0; dy < 5; dy++) {
    int hh = h + dy - 2;
    if (hh < 0 || hh >= NH) continue;
#pragma unroll
    for (int dx = 0; dx < 5; dx++) {
      int ww = w + dx - 2;
      if (ww < 0 || ww >= NW) continue;
      acc += ldin(de, ((b * NC + c) * NH + hh) * NW + ww, f) * kb[dy * 5 + dx];
    }
  }
  float g = ws[NGATE + h * NW + w];
  float e = ldin(en, ((b * NC + c) * NH2 + y) * NW2 + x, f);
  out[((b * NC + c) * NH2 + y) * NW2 + x] = g * e + (1.f - g) * acc;
}

// resolve input by flat element count (robust to permutation); fallback positional
static const void* find_by_size(void* const* d_in, const int* in_sizes, int n_in,
                                int want, int skip, const void* fb){
  int seen = 0;
  for (int i = 0; i < n_in; i++)
    if (in_sizes[i] == want) {
      if (seen == skip) return d_in[i];
      seen++;
    }
  return fb;
}

extern "C" void kernel_launch(void* const* d_in, const int* in_sizes, int n_in,
                              void* d_out, int out_size, void* d_ws, size_t ws_size,
                              hipStream_t stream) {
  (void)out_size;
  const void* en  = find_by_size(d_in, in_sizes, n_in, 4*256*128*128, 0, d_in[0]);
  const void* de  = find_by_size(d_in, in_sizes, n_in, 4*256*64*64,   0, d_in[1]);
  const void* Wg  = find_by_size(d_in, in_sizes, n_in, 256,           0, d_in[2]);
  const void* bg  = find_by_size(d_in, in_sizes, n_in, 1,             0, d_in[3]);
  const void* Wce = find_by_size(d_in, in_sizes, n_in, 6400,          0, d_in[4]);
  const void* bce = find_by_size(d_in, in_sizes, n_in, 25,            0, d_in[5]);
  const void* Wcd = find_by_size(d_in, in_sizes, n_in, 6400,          1, d_in[6]);
  const void* Wdw = find_by_size(d_in, in_sizes, n_in, 225,           0, d_in[7]);
  const void* bdw = find_by_size(d_in, in_sizes, n_in, 25,            1, d_in[8]);
  float* ws = (float*)d_ws;
  float* out = (float*)d_out;

  hipLaunchKernelGGL(k_detect, dim3(1), dim3(256), 0, stream, de, ws);
  hipLaunchKernelGGL(k_prep, dim3(25), dim3(256), 0, stream,
                     Wg, bg, Wce, bce, Wcd, Wdw, bdw, ws);

  if (ws_size >= FULL_NEED_BYTES) {
    hipLaunchKernelGGL(o1_dec_gate, dim3(NB * NH),      dim3(256), 0, stream, de, ws);
    hipLaunchKernelGGL(o3_enc,      dim3(NB * NH2),     dim3(256), 0, stream, en, ws);
    hipLaunchKernelGGL(o4_kernels,  dim3(NB * NH2 * 2), dim3(256), 0, stream, ws);
    hipLaunchKernelGGL(o2_det,      dim3(NB * 68),      dim3(256), 0, stream, de, ws);
    hipLaunchKernelGGL(o5_final,    dim3(NB * NH * 4),  dim3(256), 0, stream, en, ws, out);
  } else {
    for (int b = 0; b < NB; b++) {
      hipLaunchKernelGGL(kA_gate, dim3(16),    dim3(256), 0, stream, de, ws, b);
      hipLaunchKernelGGL(kB_dec,  dim3(16),    dim3(256), 0, stream, de, ws, b);
      hipLaunchKernelGGL(kC_enc,  dim3(64),    dim3(256), 0, stream, en, ws, b);
      hipLaunchKernelGGL(kD_kern, dim3(64),    dim3(256), 0, stream, ws);
      hipLaunchKernelGGL(kE_out,  dim3(16384), dim3(256), 0, stream, en, de, ws, out, b);
    }
  }
}

// Round 2
// 269.021 us; speedup vs baseline: 1.4143x; 1.2432x over previous
//
#include <hip/hip_runtime.h>

// FADE-Lite round 9: kill the exposed-latency conv1x1 kernels.
// o3_enc (84us, 20% occ, VALUBusy 7.5%): 2 blocks/CU and only ~2 loads in
// flight per thread. New o3: grid 1024 (half-row/block), 4 wave-aligned
// c-groups of 64, channel loop unrolled x8 with independent load temps
// (8 loads in flight/thread, 16 waves/CU -> BW-bound not latency-bound).
// o1_dec_gate had the same structure at 1 block/CU: split channels 2-way
// across blocks (partials in the then-dead ENC region, launch order
// o1a -> o1b -> o3 keeps aliasing safe), 32ch/thread unrolled x8, plus a
// trivial o1b reduce. Everything else identical to verified round 8.
//
// out = gate*en + (1-gate)*CARAFE(de, softmax_k(dw3x3(conv1x1(en,Wce))+up2(dw3x3(conv1x1(de,Wcd)))))
// B=4, C=256, H=64, W=64. Inputs fp32 (runtime-detected), output fp32.

typedef unsigned short u16;
typedef unsigned int u32;

#define NB 4
#define NC 256
#define NH 64
#define NW 64
#define NH2 128
#define NW2 128

// fp32 weights in ws (shared by both paths)
#define OFF_WG   0
#define OFF_BG   256
#define OFF_WCE  272
#define OFF_BCE  6672
#define OFF_WCD  6704
#define OFF_WDW  13104
#define OFF_BDW  13330
#define OFF_FLAG 13356    // 1.0f = fp32 inputs, 0.0f = bf16 inputs

// ---- optimized (full-batch) layout, floats ----
#define OFF_GATE 16384    // 4*4096 fp32                    -> 32768
#define OFF_KB   32768    // 4*4096*100 u16 (819200 fl)     -> 851968
#define OFF_ENC  851968   // 4*25*16384 fp32                -> 2490368
#define OFF_DEC  2490368  // 4*25*4096 fp32                 -> 2899968
#define OFF_DET  851968   // 4*68*68*256 u16, aliases dead ENC+DEC after o4 -> 3219456
#define OFF_P1   851968   // o1a partials: 2*4*26*4096 fl (851968 fl) in ENC area,
                          // consumed by o1b BEFORE o3 writes ENC.
#define FULL_NEED_BYTES 12877824ull

// ---- naive (per-batch) layout, floats ----
#define NGATE 16384
#define NDEC  20480
#define NENC  122880
#define NKBF  532480      // -> end 942080 (3.77 MB)

__device__ __forceinline__ float bf2f(u16 u){ return __uint_as_float(((u32)u) << 16); }
__device__ __forceinline__ u16 f2bf(float f){
  u32 x = __float_as_uint(f);
  return (u16)((x + 0x7fffu + ((x >> 16) & 1u)) >> 16);  // RNE (finite)
}
__device__ __forceinline__ float ldin(const void* p, int i, bool f32){
  return f32 ? ((const float*)p)[i] : bf2f(((const u16*)p)[i]);
}

// dtype detector on `de` (~N(0,1)): bf16 exp in [0x70,0x82] nearly always;
// fp32 low-mantissa u16s ~uniform (~7% hit).
__global__ __launch_bounds__(256) void k_detect(const void* de_raw, float* ws){
  __shared__ int cnt;
  if (threadIdx.x == 0) cnt = 0;
  __syncthreads();
  int c = 0;
#pragma unroll
  for (int s = 0; s < 2; s++) {
    int i = (threadIdx.x + s * 256) * 2;
    u16 u = ((const u16*)de_raw)[i];
    int e = (u >> 7) & 0xff;
    if (e >= 0x70 && e <= 0x82) c++;
  }
  atomicAdd(&cnt, c);
  __syncthreads();
  if (threadIdx.x == 0) ws[OFF_FLAG] = (cnt < 256) ? 1.0f : 0.0f;
}

__global__ __launch_bounds__(256) void k_prep(const void* Wg, const void* bg,
    const void* Wce, const void* bce, const void* Wcd, const void* Wdw, const void* bdw,
    float* ws){
  bool f = ws[OFF_FLAG] != 0.f;
  int i = threadIdx.x + blockIdx.x * 256;
  if (i < 6400) {
    ws[OFF_WCE + i] = ldin(Wce, i, f);
    ws[OFF_WCD + i] = ldin(Wcd, i, f);
    if (i < 256) ws[OFF_WG + i] = ldin(Wg, i, f);
    if (i < 1)   ws[OFF_BG + i] = ldin(bg, i, f);
    if (i < 25)  ws[OFF_BCE + i] = ldin(bce, i, f);
    if (i < 225) ws[OFF_WDW + i] = ldin(Wdw, i, f);
    if (i < 25)  ws[OFF_BDW + i] = ldin(bdw, i, f);
  }
}

// ================= optimized path =================

// o1a: partial DEC/GATE over a 128-channel chunk.
// grid = B*64*2 (512): b = bi>>7, rem&127 -> h = rem>>1, chunk = rem&1.
// block 256 = 4 waves; wave g covers channels chunk*128 + g*32 .. +31.
// Partials (raw, no bias/sigmoid) -> OFF_P1[(chunk*NB+b)*26+o][h][w].
__global__ __launch_bounds__(256) void o1a_dec_gate(const void* de, float* ws){
  __shared__ float red[4][26][64];
  bool f = ws[OFF_FLAG] != 0.f;
  int b = blockIdx.x >> 7;
  int rem = blockIdx.x & 127;
  int h = rem >> 1;
  int chunk = rem & 1;
  int g = threadIdx.x >> 6;
  int w = threadIdx.x & 63;
  int c0 = __builtin_amdgcn_readfirstlane(chunk * 128 + g * 32);
  float acc[26];
#pragma unroll
  for (int o = 0; o < 26; o++) acc[o] = 0.f;
  int idx = ((b * NC + c0) * NH + h) * NW + w;
  for (int ci = 0; ci < 32; ci += 8) {
    float v0 = ldin(de, idx,            f);
    float v1 = ldin(de, idx + 1 * 4096, f);
    float v2 = ldin(de, idx + 2 * 4096, f);
    float v3 = ldin(de, idx + 3 * 4096, f);
    float v4 = ldin(de, idx + 4 * 4096, f);
    float v5 = ldin(de, idx + 5 * 4096, f);
    float v6 = ldin(de, idx + 6 * 4096, f);
    float v7 = ldin(de, idx + 7 * 4096, f);
    idx += 8 * 4096;
    int c = c0 + ci;
    acc[25] += ws[OFF_WG + c] * v0 + ws[OFF_WG + c + 1] * v1
             + ws[OFF_WG + c + 2] * v2 + ws[OFF_WG + c + 3] * v3
             + ws[OFF_WG + c + 4] * v4 + ws[OFF_WG + c + 5] * v5
             + ws[OFF_WG + c + 6] * v6 + ws[OFF_WG + c + 7] * v7;
#pragma unroll
    for (int k = 0; k < 25; k++) {
      const float* wk = ws + OFF_WCD + k * 256 + c;
      acc[k] += wk[0] * v0 + wk[1] * v1 + wk[2] * v2 + wk[3] * v3
              + wk[4] * v4 + wk[5] * v5 + wk[6] * v6 + wk[7] * v7;
    }
  }
#pragma unroll
  for (int o = 0; o < 26; o++) red[g][o][w] = acc[o];
  __syncthreads();
  for (int item = threadIdx.x; item < 26 * 64; item += 256) {
    int o = item >> 6; int ww = item & 63;
    float s = red[0][o][ww] + red[1][o][ww] + red[2][o][ww] + red[3][o][ww];
    ws[OFF_P1 + (((chunk * NB + b) * 26 + o) << 12) + (h << 6) + ww] = s;
  }
}

// o1b: DEC = p0+p1; GATE = sigmoid(p0+p1+bg). grid = 1664*256 = NB*26*4096.
__global__ __launch_bounds__(256) void o1b_reduce(float* ws){
  int i = blockIdx.x * 256 + threadIdx.x;
  int b = i / (26 * 4096);
  int r = i - b * 26 * 4096;
  int o = r >> 12;
  int pix = r & 4095;
  float s = ws[OFF_P1 + (((0 * NB + b) * 26 + o) << 12) + pix]
          + ws[OFF_P1 + (((1 * NB + b) * 26 + o) << 12) + pix];
  if (o < 25)
    ws[OFF_DEC + ((b * 25 + o) << 12) + pix] = s;
  else {
    float z = s + ws[OFF_BG];
    ws[OFF_GATE + (b << 12) + pix] = 1.f / (1.f + __expf(-z));
  }
}

// DET[b][p][q][c] = de[b][c][p-2][q-2] (0 outside), bf16. Runs AFTER o4 (aliases ENC+DEC).
// grid = B*68, block 256 (=c)
__global__ __launch_bounds__(256) void o2_det(const void* de, float* ws){
  bool f = ws[OFF_FLAG] != 0.f;
  u16* det = (u16*)(ws + OFF_DET);
  int b = blockIdx.x / 68;
  int p = blockIdx.x % 68;
  int c = threadIdx.x;
  int h = p - 2;
  bool hv = (h >= 0 && h < NH);
  int sbase = ((b * NC + c) * NH + (hv ? h : 0)) * NW;
  u16* dst = det + ((b * 68 + p) * 68) * NC + c;
  for (int q = 0; q < 68; q++) {
    int w = q - 2;
    float v = (hv && w >= 0 && w < NW) ? ldin(de, sbase + w, f) : 0.f;
    dst[q * NC] = f2bf(v);
  }
}

// ENC = conv1x1(en, W_ce)+b_ce.
// grid = B*128*2 (1024): b = bi>>8, rem&255 -> y = rem>>1, xs = (rem&1)*64.
// block 256 = 4 waves; wave g covers channels g*64..+63, lanes = 64 x.
// Channel loop unrolled x8 with independent temps -> 8 loads in flight.
__global__ __launch_bounds__(256) void o3_enc(const void* en, float* ws){
  __shared__ float red[4][25][64];
  bool f = ws[OFF_FLAG] != 0.f;
  int b = blockIdx.x >> 8;
  int rem = blockIdx.x & 255;
  int y = rem >> 1;
  int xs = (rem & 1) << 6;
  int g = threadIdx.x >> 6;
  int xl = threadIdx.x & 63;
  int c0 = __builtin_amdgcn_readfirstlane(g * 64);
  float acc[25];
#pragma unroll
  for (int k = 0; k < 25; k++) acc[k] = 0.f;
  int idx = ((b * NC + c0) * NH2 + y) * NW2 + xs + xl;
  for (int ci = 0; ci < 64; ci += 8) {
    float v0 = ldin(en, idx,             f);
    float v1 = ldin(en, idx + 1 * 16384, f);
    float v2 = ldin(en, idx + 2 * 16384, f);
    float v3 = ldin(en, idx + 3 * 16384, f);
    float v4 = ldin(en, idx + 4 * 16384, f);
    float v5 = ldin(en, idx + 5 * 16384, f);
    float v6 = ldin(en, idx + 6 * 16384, f);
    float v7 = ldin(en, idx + 7 * 16384, f);
    idx += 8 * 16384;
    int c = c0 + ci;
#pragma unroll
    for (int k = 0; k < 25; k++) {
      const float* wk = ws + OFF_WCE + k * 256 + c;
      acc[k] += wk[0] * v0 + wk[1] * v1 + wk[2] * v2 + wk[3] * v3
              + wk[4] * v4 + wk[5] * v5 + wk[6] * v6 + wk[7] * v7;
    }
  }
#pragma unroll
  for (int k = 0; k < 25; k++) red[g][k][xl] = acc[k];
  __syncthreads();
  for (int item = threadIdx.x; item < 25 * 64; item += 256) {
    int k = item >> 6; int xx = item & 63;
    float s = red[0][k][xx] + red[1][k][xx] + red[2][k][xx] + red[3][k][xx]
            + ws[OFF_BCE + k];
    ws[OFF_ENC + ((b * 25 + k) * NH2 + y) * NW2 + xs + xx] = s;
  }
}

// raw = dw3x3(ENC)+b + up2(dw3x3(DEC)+b); softmax over 25 -> KB bf16 [b][h][w][tap*4+st]
// grid = B*128*2 (1024): each block = one output row y, 64-pixel x-strip.
// 256 threads = 4 tap-groups x 64 pixels; group tg computes taps k=tg,tg+4,...
// Partial raw values go to LDS red[25][64]; wave 0 does softmax straight from
// LDS (no 25-register array -> no scratch spill).
__global__ __launch_bounds__(256) void o4_kernels(float* ws){
  __shared__ float red[25][64];
  int b = blockIdx.x >> 8;
  int rem = blockIdx.x & 255;
  int y = rem >> 1;
  int xs = (rem & 1) << 6;
  int tg = __builtin_amdgcn_readfirstlane(threadIdx.x >> 6);
  int xl = threadIdx.x & 63;
  int x = xs + xl;
  int h = y >> 1, w = x >> 1;
  const float* enc = ws + OFF_ENC + (b * 25) * NH2 * NW2;
  const float* dec = ws + OFF_DEC + (b * 25) * NH * NW;

  for (int k = tg; k < 25; k += 4) {
    float s = 2.f * ws[OFF_BDW + k];
#pragma unroll
    for (int u = 0; u < 3; u++) {
      int yy = y + u - 1, hh = h + u - 1;
      bool yok = (yy >= 0 && yy < NH2);
      bool hok = (hh >= 0 && hh < NH);
#pragma unroll
      for (int v = 0; v < 3; v++) {
        int xx = x + v - 1, w2 = w + v - 1;
        float wd = ws[OFF_WDW + k * 9 + u * 3 + v];
        if (yok && xx >= 0 && xx < NW2)
          s += enc[(k * NH2 + yy) * NW2 + xx] * wd;
        if (hok && w2 >= 0 && w2 < NW)
          s += dec[(k * NH + hh) * NW + w2] * wd;
      }
    }
    red[k][xl] = s;
  }
  __syncthreads();

  if (threadIdx.x < 64) {
    int t = threadIdx.x;
    int xp = xs + t;
    float m = -1e30f;
#pragma unroll
    for (int k = 0; k < 25; k++) m = fmaxf(m, red[k][t]);
    float sum = 0.f;
#pragma unroll
    for (int k = 0; k < 25; k++) {
      float e = __expf(red[k][t] - m);
      red[k][t] = e;
      sum += e;
    }
    float inv = 1.f / sum;
    int st = ((y & 1) << 1) + (xp & 1);
    int wp = xp >> 1;
    u16* kbu = (u16*)(ws + OFF_KB);
    u16* dst = kbu + ((b * NH + h) * NW + wp) * 100 + st;
#pragma unroll
    for (int k = 0; k < 25; k++) dst[k * 4] = f2bf(red[k][t] * inv);
  }
}

// Channel-major carafe + gate blend, fp32 out. grid = B*64*4 (1024), block 256 (4 waves).
__global__ __launch_bounds__(256) void o5_final(const void* en, float* ws, float* out){
  __shared__ u16 stag[2][32][260];
  bool f = ws[OFF_FLAG] != 0.f;
  const u16* det = (const u16*)(ws + OFF_DET);
  const u16* kbu = (const u16*)(ws + OFF_KB);
  const float* gate = ws + OFF_GATE;

  int b = blockIdx.x >> 8;
  int rem = blockIdx.x & 255;
  int h = rem >> 2;
  int w0b = (rem & 3) * 16;
  int wave = threadIdx.x >> 6;
  int lane = threadIdx.x & 63;
  int c4 = lane * 4;

  for (int i = 0; i < 4; i++) {
    int wu = __builtin_amdgcn_readfirstlane(w0b + wave * 4 + i);
    const u16* kp = kbu + ((b * NH + h) * NW + wu) * 100;
    float acc[4][4];
#pragma unroll
    for (int st = 0; st < 4; st++)
#pragma unroll
      for (int j = 0; j < 4; j++) acc[st][j] = 0.f;

#pragma unroll
    for (int dy = 0; dy < 5; dy++) {
      const u16* dp = det + (((b * 68 + h + dy) * 68 + wu) * NC) + c4;
#pragma unroll
      for (int dx = 0; dx < 5; dx++) {
        ushort4 uv = *(const ushort4*)(dp + dx * NC);
        float v0 = bf2f(uv.x), v1 = bf2f(uv.y), v2 = bf2f(uv.z), v3 = bf2f(uv.w);
        const u32* kpu = (const u32*)(kp + (dy * 5 + dx) * 4);
        u32 k01 = kpu[0], k23 = kpu[1];
        float k0 = bf2f((u16)(k01 & 0xffffu));
        float k1 = bf2f((u16)(k01 >> 16));
        float k2 = bf2f((u16)(k23 & 0xffffu));
        float k3 = bf2f((u16)(k23 >> 16));
        acc[0][0] += k0 * v0; acc[0][1] += k0 * v1; acc[0][2] += k0 * v2; acc[0][3] += k0 * v3;
        acc[1][0] += k1 * v0; acc[1][1] += k1 * v1; acc[1][2] += k1 * v2; acc[1][3] += k1 * v3;
        acc[2][0] += k2 * v0; acc[2][1] += k2 * v1; acc[2][2] += k2 * v2; acc[2][3] += k2 * v3;
        acc[3][0] += k3 * v0; acc[3][1] += k3 * v1; acc[3][2] += k3 * v2; acc[3][3] += k3 * v3;
      }
    }
    int xl = (wave * 4 + i) * 2;
#pragma unroll
    for (int s = 0; s < 2; s++)
#pragma unroll
      for (int t = 0; t < 2; t++) {
        int st = s * 2 + t;
        ushort4 pv;
        pv.x = f2bf(acc[st][0]); pv.y = f2bf(acc[st][1]);
        pv.z = f2bf(acc[st][2]); pv.w = f2bf(acc[st][3]);
        *(ushort4*)&stag[s][xl + t][c4] = pv;
      }
  }
  __syncthreads();

  int xp = threadIdx.x & 31;
  int cb = (threadIdx.x >> 5) * 2;
  int x = w0b * 2 + xp;
  int wpix = w0b + (xp >> 1);
  float g = gate[(b * NH + h) * NW + wpix];
  float gi = 1.f - g;
#pragma unroll
  for (int pass = 0; pass < 16; pass++) {
    int c = cb + pass * 16;
#pragma unroll
    for (int s = 0; s < 2; s++) {
      int y = 2 * h + s;
      u32 rr = *(const u32*)&stag[s][xp][c];
      float cr0 = bf2f((u16)(rr & 0xffffu));
      float cr1 = bf2f((u16)(rr >> 16));
      int eidx = ((b * NC + c) * NH2 + y) * NW2 + x;
      float e0 = ldin(en, eidx, f);
      float e1 = ldin(en, eidx + NH2 * NW2, f);
      out[eidx] = g * e0 + gi * cr0;
      out[eidx + NH2 * NW2] = g * e1 + gi * cr1;
    }
  }
}

// ================= naive fallback path (verified round 6) =================

__global__ __launch_bounds__(256) void kA_gate(const void* de, float* ws, int b){
  bool f = ws[OFF_FLAG] != 0.f;
  int idx = blockIdx.x * 256 + threadIdx.x;
  int h = idx >> 6, w = idx & 63;
  float s = ws[OFF_BG];
  for (int c = 0; c < NC; c++)
    s += ldin(de, ((b * NC + c) * NH + h) * NW + w, f) * ws[OFF_WG + c];
  ws[NGATE + idx] = 1.f / (1.f + __expf(-s));
}

__global__ __launch_bounds__(256) void kB_dec(const void* de, float* ws, int b){
  bool f = ws[OFF_FLAG] != 0.f;
  int idx = blockIdx.x * 256 + threadIdx.x;
  int h = idx >> 6, w = idx & 63;
  float acc[25];
#pragma unroll
  for (int k = 0; k < 25; k++) acc[k] = 0.f;
  for (int c = 0; c < NC; c++) {
    float v = ldin(de, ((b * NC + c) * NH + h) * NW + w, f);
#pragma unroll
    for (int k = 0; k < 25; k++) acc[k] += v * ws[OFF_WCD + k * 256 + c];
  }
#pragma unroll
  for (int k = 0; k < 25; k++)
    ws[NDEC + (k * NH + h) * NW + w] = acc[k];
}

__global__ __launch_bounds__(256) void kC_enc(const void* en, float* ws, int b){
  bool f = ws[OFF_FLAG] != 0.f;
  int idx = blockIdx.x * 256 + threadIdx.x;
  int y = idx >> 7, x = idx & 127;
  float acc[25];
#pragma unroll
  for (int k = 0; k < 25; k++) acc[k] = 0.f;
  for (int c = 0; c < NC; c++) {
    float v = ldin(en, ((b * NC + c) * NH2 + y) * NW2 + x, f);
#pragma unroll
    for (int k = 0; k < 25; k++) acc[k] += v * ws[OFF_WCE + k * 256 + c];
  }
#pragma unroll
  for (int k = 0; k < 25; k++)
    ws[NENC + (k * NH2 + y) * NW2 + x] = acc[k] + ws[OFF_BCE + k];
}

__global__ __launch_bounds__(256) void kD_kern(float* ws){
  int idx = blockIdx.x * 256 + threadIdx.x;
  int y = idx >> 7, x = idx & 127;
  int h = y >> 1, w = x >> 1;
  float raw[25];
#pragma unroll
  for (int k = 0; k < 25; k++) {
    float s = 2.f * ws[OFF_BDW + k];
#pragma unroll
    for (int u = 0; u < 3; u++) {
      int yy = y + u - 1, hh = h + u - 1;
#pragma unroll
      for (int v = 0; v < 3; v++) {
        int xx = x + v - 1, ww = w + v - 1;
        float wd = ws[OFF_WDW + k * 9 + u * 3 + v];
        if (yy >= 0 && yy < NH2 && xx >= 0 && xx < NW2)
          s += ws[NENC + (k * NH2 + yy) * NW2 + xx] * wd;
        if (hh >= 0 && hh < NH && ww >= 0 && ww < NW)
          s += ws[NDEC + (k * NH + hh) * NW + ww] * wd;
      }
    }
    raw[k] = s;
  }
  float m = raw[0];
#pragma unroll
  for (int k = 1; k < 25; k++) m = fmaxf(m, raw[k]);
  float sum = 0.f;
#pragma unroll
  for (int k = 0; k < 25; k++) { raw[k] = __expf(raw[k] - m); sum += raw[k]; }
  float inv = 1.f / sum;
  float* dst = ws + NKBF + idx * 25;
#pragma unroll
  for (int k = 0; k < 25; k++) dst[k] = raw[k] * inv;
}

__global__ __launch_bounds__(256) void kE_out(const void* en, const void* de,
    const float* ws, float* out, int b){
  bool f = ws[OFF_FLAG] != 0.f;
  int idx = blockIdx.x * 256 + threadIdx.x;
  int c = idx >> 14;
  int y = (idx >> 7) & 127;
  int x = idx & 127;
  int h = y >> 1, w = x >> 1;
  const float* kb = ws + NKBF + (y * NW2 + x) * 25;
  float acc = 0.f;
#pragma unroll
  for (int dy = 0; dy < 5; dy++) {
    int hh = h + dy - 2;
    if (hh < 0 || hh >= NH) continue;
#pragma unroll
    for (int dx = 0; dx < 5; dx++) {
      int ww = w + dx - 2;
      if (ww < 0 || ww >= NW) continue;
      acc += ldin(de, ((b * NC + c) * NH + hh) * NW + ww, f) * kb[dy * 5 + dx];
    }
  }
  float g = ws[NGATE + h * NW + w];
  float e = ldin(en, ((b * NC + c) * NH2 + y) * NW2 + x, f);
  out[((b * NC + c) * NH2 + y) * NW2 + x] = g * e + (1.f - g) * acc;
}

// resolve input by flat element count (robust to permutation); fallback positional
static const void* find_by_size(void* const* d_in, const int* in_sizes, int n_in,
                                int want, int skip, const void* fb){
  int seen = 0;
  for (int i = 0; i < n_in; i++)
    if (in_sizes[i] == want) {
      if (seen == skip) return d_in[i];
      seen++;
    }
  return fb;
}

extern "C" void kernel_launch(void* const* d_in, const int* in_sizes, int n_in,
                              void* d_out, int out_size, void* d_ws, size_t ws_size,
                              hipStream_t stream) {
  (void)out_size;
  const void* en  = find_by_size(d_in, in_sizes, n_in, 4*256*128*128, 0, d_in[0]);
  const void* de  = find_by_size(d_in, in_sizes, n_in, 4*256*64*64,   0, d_in[1]);
  const void* Wg  = find_by_size(d_in, in_sizes, n_in, 256,           0, d_in[2]);
  const void* bg  = find_by_size(d_in, in_sizes, n_in, 1,             0, d_in[3]);
  const void* Wce = find_by_size(d_in, in_sizes, n_in, 6400,          0, d_in[4]);
  const void* bce = find_by_size(d_in, in_sizes, n_in, 25,            0, d_in[5]);
  const void* Wcd = find_by_size(d_in, in_sizes, n_in, 6400,          1, d_in[6]);
  const void* Wdw = find_by_size(d_in, in_sizes, n_in, 225,           0, d_in[7]);
  const void* bdw = find_by_size(d_in, in_sizes, n_in, 25,            1, d_in[8]);
  float* ws = (float*)d_ws;
  float* out = (float*)d_out;

  hipLaunchKernelGGL(k_detect, dim3(1), dim3(256), 0, stream, de, ws);
  hipLaunchKernelGGL(k_prep, dim3(25), dim3(256), 0, stream,
                     Wg, bg, Wce, bce, Wcd, Wdw, bdw, ws);

  if (ws_size >= FULL_NEED_BYTES) {
    hipLaunchKernelGGL(o1a_dec_gate, dim3(NB * NH * 2),  dim3(256), 0, stream, de, ws);
    hipLaunchKernelGGL(o1b_reduce,   dim3(1664),         dim3(256), 0, stream, ws);
    hipLaunchKernelGGL(o3_enc,       dim3(NB * NH2 * 2), dim3(256), 0, stream, en, ws);
    hipLaunchKernelGGL(o4_kernels,   dim3(NB * NH2 * 2), dim3(256), 0, stream, ws);
    hipLaunchKernelGGL(o2_det,       dim3(NB * 68),      dim3(256), 0, stream, de, ws);
    hipLaunchKernelGGL(o5_final,     dim3(NB * NH * 4),  dim3(256), 0, stream, en, ws, out);
  } else {
    for (int b = 0; b < NB; b++) {
      hipLaunchKernelGGL(kA_gate, dim3(16),    dim3(256), 0, stream, de, ws, b);
      hipLaunchKernelGGL(kB_dec,  dim3(16),    dim3(256), 0, stream, de, ws, b);
      hipLaunchKernelGGL(kC_enc,  dim3(64),    dim3(256), 0, stream, en, ws, b);
      hipLaunchKernelGGL(kD_kern, dim3(64),    dim3(256), 0, stream, ws);
      hipLaunchKernelGGL(kE_out,  dim3(16384), dim3(256), 0, stream, en, de, ws, out, b);
    }
  }
}

// Round 3
// 249.330 us; speedup vs baseline: 1.5260x; 1.0790x over previous
//
#include <hip/hip_runtime.h>

// FADE-Lite round 10: break o5's phase lockstep + fix o2's transposed reads.
// o5 (47us, BW 31%, VALU 37%, occ 33%): two-phase kernel at 4 blocks/CU in
// lockstep -> split by output row s: grid 2048, LDS 16.6KB, 8 blocks/CU,
// acc[2][4]; XCD swizzle co-locates (pid,s) pairs so the doubled DET L2
// traffic stays local; nontemporal out stores. o2: LDS-transpose rewrite,
// grid 1088, coalesced de reads (lanes across w) -> tile[64][65] -> coalesced
// DET writes (lanes across c). Everything else identical to verified round 9.
//
// out = gate*en + (1-gate)*CARAFE(de, softmax_k(dw3x3(conv1x1(en,Wce))+up2(dw3x3(conv1x1(de,Wcd)))))
// B=4, C=256, H=64, W=64. Inputs fp32 (runtime-detected), output fp32.

typedef unsigned short u16;
typedef unsigned int u32;

#define NB 4
#define NC 256
#define NH 64
#define NW 64
#define NH2 128
#define NW2 128

// fp32 weights in ws (shared by both paths)
#define OFF_WG   0
#define OFF_BG   256
#define OFF_WCE  272
#define OFF_BCE  6672
#define OFF_WCD  6704
#define OFF_WDW  13104
#define OFF_BDW  13330
#define OFF_FLAG 13356    // 1.0f = fp32 inputs, 0.0f = bf16 inputs

// ---- optimized (full-batch) layout, floats ----
#define OFF_GATE 16384    // 4*4096 fp32                    -> 32768
#define OFF_KB   32768    // 4*4096*100 u16 (819200 fl)     -> 851968
#define OFF_ENC  851968   // 4*25*16384 fp32                -> 2490368
#define OFF_DEC  2490368  // 4*25*4096 fp32                 -> 2899968
#define OFF_DET  851968   // 4*68*68*256 u16, aliases dead ENC+DEC after o4 -> 3219456
#define OFF_P1   851968   // o1a partials: 2*4*26*4096 fl in ENC area,
                          // consumed by o1b BEFORE o3 writes ENC.
#define FULL_NEED_BYTES 12877824ull

// ---- naive (per-batch) layout, floats ----
#define NGATE 16384
#define NDEC  20480
#define NENC  122880
#define NKBF  532480      // -> end 942080 (3.77 MB)

__device__ __forceinline__ float bf2f(u16 u){ return __uint_as_float(((u32)u) << 16); }
__device__ __forceinline__ u16 f2bf(float f){
  u32 x = __float_as_uint(f);
  return (u16)((x + 0x7fffu + ((x >> 16) & 1u)) >> 16);  // RNE (finite)
}
__device__ __forceinline__ float ldin(const void* p, int i, bool f32){
  return f32 ? ((const float*)p)[i] : bf2f(((const u16*)p)[i]);
}

// dtype detector on `de` (~N(0,1)): bf16 exp in [0x70,0x82] nearly always;
// fp32 low-mantissa u16s ~uniform (~7% hit).
__global__ __launch_bounds__(256) void k_detect(const void* de_raw, float* ws){
  __shared__ int cnt;
  if (threadIdx.x == 0) cnt = 0;
  __syncthreads();
  int c = 0;
#pragma unroll
  for (int s = 0; s < 2; s++) {
    int i = (threadIdx.x + s * 256) * 2;
    u16 u = ((const u16*)de_raw)[i];
    int e = (u >> 7) & 0xff;
    if (e >= 0x70 && e <= 0x82) c++;
  }
  atomicAdd(&cnt, c);
  __syncthreads();
  if (threadIdx.x == 0) ws[OFF_FLAG] = (cnt < 256) ? 1.0f : 0.0f;
}

__global__ __launch_bounds__(256) void k_prep(const void* Wg, const void* bg,
    const void* Wce, const void* bce, const void* Wcd, const void* Wdw, const void* bdw,
    float* ws){
  bool f = ws[OFF_FLAG] != 0.f;
  int i = threadIdx.x + blockIdx.x * 256;
  if (i < 6400) {
    ws[OFF_WCE + i] = ldin(Wce, i, f);
    ws[OFF_WCD + i] = ldin(Wcd, i, f);
    if (i < 256) ws[OFF_WG + i] = ldin(Wg, i, f);
    if (i < 1)   ws[OFF_BG + i] = ldin(bg, i, f);
    if (i < 25)  ws[OFF_BCE + i] = ldin(bce, i, f);
    if (i < 225) ws[OFF_WDW + i] = ldin(Wdw, i, f);
    if (i < 25)  ws[OFF_BDW + i] = ldin(bdw, i, f);
  }
}

// ================= optimized path =================

// o1a: partial DEC/GATE over a 128-channel chunk.
// grid = B*64*2 (512): b = bi>>7, rem&127 -> h = rem>>1, chunk = rem&1.
// block 256 = 4 waves; wave g covers channels chunk*128 + g*32 .. +31.
// Partials (raw, no bias/sigmoid) -> OFF_P1[(chunk*NB+b)*26+o][h][w].
__global__ __launch_bounds__(256) void o1a_dec_gate(const void* de, float* ws){
  __shared__ float red[4][26][64];
  bool f = ws[OFF_FLAG] != 0.f;
  int b = blockIdx.x >> 7;
  int rem = blockIdx.x & 127;
  int h = rem >> 1;
  int chunk = rem & 1;
  int g = threadIdx.x >> 6;
  int w = threadIdx.x & 63;
  int c0 = __builtin_amdgcn_readfirstlane(chunk * 128 + g * 32);
  float acc[26];
#pragma unroll
  for (int o = 0; o < 26; o++) acc[o] = 0.f;
  int idx = ((b * NC + c0) * NH + h) * NW + w;
  for (int ci = 0; ci < 32; ci += 8) {
    float v0 = ldin(de, idx,            f);
    float v1 = ldin(de, idx + 1 * 4096, f);
    float v2 = ldin(de, idx + 2 * 4096, f);
    float v3 = ldin(de, idx + 3 * 4096, f);
    float v4 = ldin(de, idx + 4 * 4096, f);
    float v5 = ldin(de, idx + 5 * 4096, f);
    float v6 = ldin(de, idx + 6 * 4096, f);
    float v7 = ldin(de, idx + 7 * 4096, f);
    idx += 8 * 4096;
    int c = c0 + ci;
    acc[25] += ws[OFF_WG + c] * v0 + ws[OFF_WG + c + 1] * v1
             + ws[OFF_WG + c + 2] * v2 + ws[OFF_WG + c + 3] * v3
             + ws[OFF_WG + c + 4] * v4 + ws[OFF_WG + c + 5] * v5
             + ws[OFF_WG + c + 6] * v6 + ws[OFF_WG + c + 7] * v7;
#pragma unroll
    for (int k = 0; k < 25; k++) {
      const float* wk = ws + OFF_WCD + k * 256 + c;
      acc[k] += wk[0] * v0 + wk[1] * v1 + wk[2] * v2 + wk[3] * v3
              + wk[4] * v4 + wk[5] * v5 + wk[6] * v6 + wk[7] * v7;
    }
  }
#pragma unroll
  for (int o = 0; o < 26; o++) red[g][o][w] = acc[o];
  __syncthreads();
  for (int item = threadIdx.x; item < 26 * 64; item += 256) {
    int o = item >> 6; int ww = item & 63;
    float s = red[0][o][ww] + red[1][o][ww] + red[2][o][ww] + red[3][o][ww];
    ws[OFF_P1 + (((chunk * NB + b) * 26 + o) << 12) + (h << 6) + ww] = s;
  }
}

// o1b: DEC = p0+p1; GATE = sigmoid(p0+p1+bg). grid = 1664*256 = NB*26*4096.
__global__ __launch_bounds__(256) void o1b_reduce(float* ws){
  int i = blockIdx.x * 256 + threadIdx.x;
  int b = i / (26 * 4096);
  int r = i - b * 26 * 4096;
  int o = r >> 12;
  int pix = r & 4095;
  float s = ws[OFF_P1 + (((0 * NB + b) * 26 + o) << 12) + pix]
          + ws[OFF_P1 + (((1 * NB + b) * 26 + o) << 12) + pix];
  if (o < 25)
    ws[OFF_DEC + ((b * 25 + o) << 12) + pix] = s;
  else {
    float z = s + ws[OFF_BG];
    ws[OFF_GATE + (b << 12) + pix] = 1.f / (1.f + __expf(-z));
  }
}

// DET[b][p][q][c] = de[b][c][p-2][q-2] (0 outside), bf16. Runs AFTER o4 (aliases ENC+DEC).
// grid = B*68*4 (1088): b = bi/272, r = bi%272, p = r>>2, c-chunk = (r&3)*64.
// Coalesced de reads (lanes across w) -> LDS transpose tile[64][65] (stride-65,
// 2-way = free) -> coalesced DET writes (lanes across c).
__global__ __launch_bounds__(256) void o2_det(const void* de, float* ws){
  __shared__ float tile[64][65];
  bool f = ws[OFF_FLAG] != 0.f;
  u16* det = (u16*)(ws + OFF_DET);
  int b = blockIdx.x / 272;
  int r = blockIdx.x % 272;
  int p = r >> 2;
  int c0 = (r & 3) << 6;
  int h = p - 2;
  bool hv = (h >= 0 && h < NH);
  for (int item = threadIdx.x; item < 64 * 64; item += 256) {
    int cl = item >> 6, w = item & 63;
    float v = hv ? ldin(de, ((b * NC + c0 + cl) * NH + h) * NW + w, f) : 0.f;
    tile[w][cl] = v;
  }
  __syncthreads();
  u16* dst = det + ((b * 68 + p) * 68) * NC + c0;
  for (int item = threadIdx.x; item < 68 * 64; item += 256) {
    int q = item >> 6, cl = item & 63;
    int w = q - 2;
    float v = (w >= 0 && w < NW) ? tile[w][cl] : 0.f;
    dst[q * NC + cl] = f2bf(v);
  }
}

// ENC = conv1x1(en, W_ce)+b_ce.
// grid = B*128*2 (1024): b = bi>>8, rem&255 -> y = rem>>1, xs = (rem&1)*64.
// block 256 = 4 waves; wave g covers channels g*64..+63, lanes = 64 x.
// Channel loop unrolled x8 with independent temps -> 8 loads in flight.
__global__ __launch_bounds__(256) void o3_enc(const void* en, float* ws){
  __shared__ float red[4][25][64];
  bool f = ws[OFF_FLAG] != 0.f;
  int b = blockIdx.x >> 8;
  int rem = blockIdx.x & 255;
  int y = rem >> 1;
  int xs = (rem & 1) << 6;
  int g = threadIdx.x >> 6;
  int xl = threadIdx.x & 63;
  int c0 = __builtin_amdgcn_readfirstlane(g * 64);
  float acc[25];
#pragma unroll
  for (int k = 0; k < 25; k++) acc[k] = 0.f;
  int idx = ((b * NC + c0) * NH2 + y) * NW2 + xs + xl;
  for (int ci = 0; ci < 64; ci += 8) {
    float v0 = ldin(en, idx,             f);
    float v1 = ldin(en, idx + 1 * 16384, f);
    float v2 = ldin(en, idx + 2 * 16384, f);
    float v3 = ldin(en, idx + 3 * 16384, f);
    float v4 = ldin(en, idx + 4 * 16384, f);
    float v5 = ldin(en, idx + 5 * 16384, f);
    float v6 = ldin(en, idx + 6 * 16384, f);
    float v7 = ldin(en, idx + 7 * 16384, f);
    idx += 8 * 16384;
    int c = c0 + ci;
#pragma unroll
    for (int k = 0; k < 25; k++) {
      const float* wk = ws + OFF_WCE + k * 256 + c;
      acc[k] += wk[0] * v0 + wk[1] * v1 + wk[2] * v2 + wk[3] * v3
              + wk[4] * v4 + wk[5] * v5 + wk[6] * v6 + wk[7] * v7;
    }
  }
#pragma unroll
  for (int k = 0; k < 25; k++) red[g][k][xl] = acc[k];
  __syncthreads();
  for (int item = threadIdx.x; item < 25 * 64; item += 256) {
    int k = item >> 6; int xx = item & 63;
    float s = red[0][k][xx] + red[1][k][xx] + red[2][k][xx] + red[3][k][xx]
            + ws[OFF_BCE + k];
    ws[OFF_ENC + ((b * 25 + k) * NH2 + y) * NW2 + xs + xx] = s;
  }
}

// raw = dw3x3(ENC)+b + up2(dw3x3(DEC)+b); softmax over 25 -> KB bf16 [b][h][w][tap*4+st]
// grid = B*128*2 (1024): each block = one output row y, 64-pixel x-strip.
// 256 threads = 4 tap-groups x 64 pixels; group tg computes taps k=tg,tg+4,...
// Partial raw values go to LDS red[25][64]; wave 0 does softmax straight from
// LDS (no 25-register array -> no scratch spill).
__global__ __launch_bounds__(256) void o4_kernels(float* ws){
  __shared__ float red[25][64];
  int b = blockIdx.x >> 8;
  int rem = blockIdx.x & 255;
  int y = rem >> 1;
  int xs = (rem & 1) << 6;
  int tg = __builtin_amdgcn_readfirstlane(threadIdx.x >> 6);
  int xl = threadIdx.x & 63;
  int x = xs + xl;
  int h = y >> 1, w = x >> 1;
  const float* enc = ws + OFF_ENC + (b * 25) * NH2 * NW2;
  const float* dec = ws + OFF_DEC + (b * 25) * NH * NW;

  for (int k = tg; k < 25; k += 4) {
    float s = 2.f * ws[OFF_BDW + k];
#pragma unroll
    for (int u = 0; u < 3; u++) {
      int yy = y + u - 1, hh = h + u - 1;
      bool yok = (yy >= 0 && yy < NH2);
      bool hok = (hh >= 0 && hh < NH);
#pragma unroll
      for (int v = 0; v < 3; v++) {
        int xx = x + v - 1, w2 = w + v - 1;
        float wd = ws[OFF_WDW + k * 9 + u * 3 + v];
        if (yok && xx >= 0 && xx < NW2)
          s += enc[(k * NH2 + yy) * NW2 + xx] * wd;
        if (hok && w2 >= 0 && w2 < NW)
          s += dec[(k * NH + hh) * NW + w2] * wd;
      }
    }
    red[k][xl] = s;
  }
  __syncthreads();

  if (threadIdx.x < 64) {
    int t = threadIdx.x;
    int xp = xs + t;
    float m = -1e30f;
#pragma unroll
    for (int k = 0; k < 25; k++) m = fmaxf(m, red[k][t]);
    float sum = 0.f;
#pragma unroll
    for (int k = 0; k < 25; k++) {
      float e = __expf(red[k][t] - m);
      red[k][t] = e;
      sum += e;
    }
    float inv = 1.f / sum;
    int st = ((y & 1) << 1) + (xp & 1);
    int wp = xp >> 1;
    u16* kbu = (u16*)(ws + OFF_KB);
    u16* dst = kbu + ((b * NH + h) * NW + wp) * 100 + st;
#pragma unroll
    for (int k = 0; k < 25; k++) dst[k * 4] = f2bf(red[k][t] * inv);
  }
}

// Channel-major carafe + gate blend, fp32 out.
// grid = B*64*4*2 (2048), block 256 (4 waves). Split by output row s (halved
// phase-1 work + LDS -> 8 blocks/CU breaks the phase lockstep). Swizzle puts
// the (pid, s=0/1) pair on the same XCD (bi%8 round-robin assumption, perf-only):
// xcd = bi&7, slot = bi>>3, s = slot&1, pid = ((slot>>1)<<3)|xcd.
__global__ __launch_bounds__(256) void o5_final(const void* en, float* ws, float* out){
  __shared__ u16 stag[32][260];
  bool f = ws[OFF_FLAG] != 0.f;
  const u16* det = (const u16*)(ws + OFF_DET);
  const u16* kbu = (const u16*)(ws + OFF_KB);
  const float* gate = ws + OFF_GATE;

  int bi = blockIdx.x;
  int xcd = bi & 7;
  int slot = bi >> 3;
  int s = slot & 1;
  int pid = ((slot >> 1) << 3) | xcd;
  int b = pid >> 8;
  int rem = pid & 255;
  int h = rem >> 2;
  int w0b = (rem & 3) * 16;
  int wave = threadIdx.x >> 6;
  int lane = threadIdx.x & 63;
  int c4 = lane * 4;

  for (int i = 0; i < 4; i++) {
    int wu = __builtin_amdgcn_readfirstlane(w0b + wave * 4 + i);
    const u16* kp = kbu + ((b * NH + h) * NW + wu) * 100 + s * 2;
    float acc[2][4];
#pragma unroll
    for (int t = 0; t < 2; t++)
#pragma unroll
      for (int j = 0; j < 4; j++) acc[t][j] = 0.f;

#pragma unroll
    for (int dy = 0; dy < 5; dy++) {
      const u16* dp = det + (((b * 68 + h + dy) * 68 + wu) * NC) + c4;
#pragma unroll
      for (int dx = 0; dx < 5; dx++) {
        ushort4 uv = *(const ushort4*)(dp + dx * NC);
        float v0 = bf2f(uv.x), v1 = bf2f(uv.y), v2 = bf2f(uv.z), v3 = bf2f(uv.w);
        u32 kk = *(const u32*)(kp + (dy * 5 + dx) * 4);
        float k0 = bf2f((u16)(kk & 0xffffu));
        float k1 = bf2f((u16)(kk >> 16));
        acc[0][0] += k0 * v0; acc[0][1] += k0 * v1; acc[0][2] += k0 * v2; acc[0][3] += k0 * v3;
        acc[1][0] += k1 * v0; acc[1][1] += k1 * v1; acc[1][2] += k1 * v2; acc[1][3] += k1 * v3;
      }
    }
    int xl = (wave * 4 + i) * 2;
#pragma unroll
    for (int t = 0; t < 2; t++) {
      ushort4 pv;
      pv.x = f2bf(acc[t][0]); pv.y = f2bf(acc[t][1]);
      pv.z = f2bf(acc[t][2]); pv.w = f2bf(acc[t][3]);
      *(ushort4*)&stag[xl + t][c4] = pv;
    }
  }
  __syncthreads();

  int xp = threadIdx.x & 31;
  int cb = (threadIdx.x >> 5) * 2;
  int x = w0b * 2 + xp;
  int wpix = w0b + (xp >> 1);
  int y = 2 * h + s;
  float g = gate[(b * NH + h) * NW + wpix];
  float gi = 1.f - g;
#pragma unroll
  for (int pass = 0; pass < 16; pass++) {
    int c = cb + pass * 16;
    u32 rr = *(const u32*)&stag[xp][c];
    float cr0 = bf2f((u16)(rr & 0xffffu));
    float cr1 = bf2f((u16)(rr >> 16));
    int eidx = ((b * NC + c) * NH2 + y) * NW2 + x;
    float e0 = ldin(en, eidx, f);
    float e1 = ldin(en, eidx + NH2 * NW2, f);
    __builtin_nontemporal_store(g * e0 + gi * cr0, &out[eidx]);
    __builtin_nontemporal_store(g * e1 + gi * cr1, &out[eidx + NH2 * NW2]);
  }
}

// ================= naive fallback path (verified round 6) =================

__global__ __launch_bounds__(256) void kA_gate(const void* de, float* ws, int b){
  bool f = ws[OFF_FLAG] != 0.f;
  int idx = blockIdx.x * 256 + threadIdx.x;
  int h = idx >> 6, w = idx & 63;
  float s = ws[OFF_BG];
  for (int c = 0; c < NC; c++)
    s += ldin(de, ((b * NC + c) * NH + h) * NW + w, f) * ws[OFF_WG + c];
  ws[NGATE + idx] = 1.f / (1.f + __expf(-s));
}

__global__ __launch_bounds__(256) void kB_dec(const void* de, float* ws, int b){
  bool f = ws[OFF_FLAG] != 0.f;
  int idx = blockIdx.x * 256 + threadIdx.x;
  int h = idx >> 6, w = idx & 63;
  float acc[25];
#pragma unroll
  for (int k = 0; k < 25; k++) acc[k] = 0.f;
  for (int c = 0; c < NC; c++) {
    float v = ldin(de, ((b * NC + c) * NH + h) * NW + w, f);
#pragma unroll
    for (int k = 0; k < 25; k++) acc[k] += v * ws[OFF_WCD + k * 256 + c];
  }
#pragma unroll
  for (int k = 0; k < 25; k++)
    ws[NDEC + (k * NH + h) * NW + w] = acc[k];
}

__global__ __launch_bounds__(256) void kC_enc(const void* en, float* ws, int b){
  bool f = ws[OFF_FLAG] != 0.f;
  int idx = blockIdx.x * 256 + threadIdx.x;
  int y = idx >> 7, x = idx & 127;
  float acc[25];
#pragma unroll
  for (int k = 0; k < 25; k++) acc[k] = 0.f;
  for (int c = 0; c < NC; c++) {
    float v = ldin(en, ((b * NC + c) * NH2 + y) * NW2 + x, f);
#pragma unroll
    for (int k = 0; k < 25; k++) acc[k] += v * ws[OFF_WCE + k * 256 + c];
  }
#pragma unroll
  for (int k = 0; k < 25; k++)
    ws[NENC + (k * NH2 + y) * NW2 + x] = acc[k] + ws[OFF_BCE + k];
}

__global__ __launch_bounds__(256) void kD_kern(float* ws){
  int idx = blockIdx.x * 256 + threadIdx.x;
  int y = idx >> 7, x = idx & 127;
  int h = y >> 1, w = x >> 1;
  float raw[25];
#pragma unroll
  for (int k = 0; k < 25; k++) {
    float s = 2.f * ws[OFF_BDW + k];
#pragma unroll
    for (int u = 0; u < 3; u++) {
      int yy = y + u - 1, hh = h + u - 1;
#pragma unroll
      for (int v = 0; v < 3; v++) {
        int xx = x + v - 1, ww = w + v - 1;
        float wd = ws[OFF_WDW + k * 9 + u * 3 + v];
        if (yy >= 0 && yy < NH2 && xx >= 0 && xx < NW2)
          s += ws[NENC + (k * NH2 + yy) * NW2 + xx] * wd;
        if (hh >= 0 && hh < NH && ww >= 0 && ww < NW)
          s += ws[NDEC + (k * NH + hh) * NW + ww] * wd;
      }
    }
    raw[k] = s;
  }
  float m = raw[0];
#pragma unroll
  for (int k = 1; k < 25; k++) m = fmaxf(m, raw[k]);
  float sum = 0.f;
#pragma unroll
  for (int k = 0; k < 25; k++) { raw[k] = __expf(raw[k] - m); sum += raw[k]; }
  float inv = 1.f / sum;
  float* dst = ws + NKBF + idx * 25;
#pragma unroll
  for (int k = 0; k < 25; k++) dst[k] = raw[k] * inv;
}

__global__ __launch_bounds__(256) void kE_out(const void* en, const void* de,
    const float* ws, float* out, int b){
  bool f = ws[OFF_FLAG] != 0.f;
  int idx = blockIdx.x * 256 + threadIdx.x;
  int c = idx >> 14;
  int y = (idx >> 7) & 127;
  int x = idx & 127;
  int h = y >> 1, w = x >> 1;
  const float* kb = ws + NKBF + (y * NW2 + x) * 25;
  float acc = 0.f;
#pragma unroll
  for (int dy = 0; dy < 5; dy++) {
    int hh = h + dy - 2;
    if (hh < 0 || hh >= NH) continue;
#pragma unroll
    for (int dx = 0; dx < 5; dx++) {
      int ww = w + dx - 2;
      if (ww < 0 || ww >= NW) continue;
      acc += ldin(de, ((b * NC + c) * NH + hh) * NW + ww, f) * kb[dy * 5 + dx];
    }
  }
  float g = ws[NGATE + h * NW + w];
  float e = ldin(en, ((b * NC + c) * NH2 + y) * NW2 + x, f);
  out[((b * NC + c) * NH2 + y) * NW2 + x] = g * e + (1.f - g) * acc;
}

// resolve input by flat element count (robust to permutation); fallback positional
static const void* find_by_size(void* const* d_in, const int* in_sizes, int n_in,
                                int want, int skip, const void* fb){
  int seen = 0;
  for (int i = 0; i < n_in; i++)
    if (in_sizes[i] == want) {
      if (seen == skip) return d_in[i];
      seen++;
    }
  return fb;
}

extern "C" void kernel_launch(void* const* d_in, const int* in_sizes, int n_in,
                              void* d_out, int out_size, void* d_ws, size_t ws_size,
                              hipStream_t stream) {
  (void)out_size;
  const void* en  = find_by_size(d_in, in_sizes, n_in, 4*256*128*128, 0, d_in[0]);
  const void* de  = find_by_size(d_in, in_sizes, n_in, 4*256*64*64,   0, d_in[1]);
  const void* Wg  = find_by_size(d_in, in_sizes, n_in, 256,           0, d_in[2]);
  const void* bg  = find_by_size(d_in, in_sizes, n_in, 1,             0, d_in[3]);
  const void* Wce = find_by_size(d_in, in_sizes, n_in, 6400,          0, d_in[4]);
  const void* bce = find_by_size(d_in, in_sizes, n_in, 25,            0, d_in[5]);
  const void* Wcd = find_by_size(d_in, in_sizes, n_in, 6400,          1, d_in[6]);
  const void* Wdw = find_by_size(d_in, in_sizes, n_in, 225,           0, d_in[7]);
  const void* bdw = find_by_size(d_in, in_sizes, n_in, 25,            1, d_in[8]);
  float* ws = (float*)d_ws;
  float* out = (float*)d_out;

  hipLaunchKernelGGL(k_detect, dim3(1), dim3(256), 0, stream, de, ws);
  hipLaunchKernelGGL(k_prep, dim3(25), dim3(256), 0, stream,
                     Wg, bg, Wce, bce, Wcd, Wdw, bdw, ws);

  if (ws_size >= FULL_NEED_BYTES) {
    hipLaunchKernelGGL(o1a_dec_gate, dim3(NB * NH * 2),     dim3(256), 0, stream, de, ws);
    hipLaunchKernelGGL(o1b_reduce,   dim3(1664),            dim3(256), 0, stream, ws);
    hipLaunchKernelGGL(o3_enc,       dim3(NB * NH2 * 2),    dim3(256), 0, stream, en, ws);
    hipLaunchKernelGGL(o4_kernels,   dim3(NB * NH2 * 2),    dim3(256), 0, stream, ws);
    hipLaunchKernelGGL(o2_det,       dim3(NB * 68 * 4),     dim3(256), 0, stream, de, ws);
    hipLaunchKernelGGL(o5_final,     dim3(NB * NH * 4 * 2), dim3(256), 0, stream, en, ws, out);
  } else {
    for (int b = 0; b < NB; b++) {
      hipLaunchKernelGGL(kA_gate, dim3(16),    dim3(256), 0, stream, de, ws, b);
      hipLaunchKernelGGL(kB_dec,  dim3(16),    dim3(256), 0, stream, de, ws, b);
      hipLaunchKernelGGL(kC_enc,  dim3(64),    dim3(256), 0, stream, en, ws, b);
      hipLaunchKernelGGL(kD_kern, dim3(64),    dim3(256), 0, stream, ws);
      hipLaunchKernelGGL(kE_out,  dim3(16384), dim3(256), 0, stream, en, de, ws, out, b);
    }
  }
}

// Round 4
// 239.925 us; speedup vs baseline: 1.5858x; 1.0392x over previous
//
#include <hip/hip_runtime.h>

// FADE-Lite round 11: o5 phase-1 VALU diet.
// r10 post-mortem: o5 44.5us, VALUBusy 34.7% (~15.4us issue) -> phase 1 is
// 1400 VALU/thread (800 scalar FMA + unpack) + 100 redundant DET loads.
// Fix: (a) dy-outer restructure - one acc block for all 4 wu of the wave,
// 8 unique DET columns loaded once per dy (j=i+dx in [0,8)): loads 100->40;
// (b) v_pk_fma_f32 (packed f32, 2 FMA/inst - this IS the 157 TF spec path)
// with op_sel broadcast of the k pair: per tap 4 v-ops + 2 k-ops + 4 pk_fma
// = 10 VALU vs 14, FMA issue halved. VGPR ~64 keeps 8 waves/SIMD.
// Everything else identical to verified round 10.
//
// out = gate*en + (1-gate)*CARAFE(de, softmax_k(dw3x3(conv1x1(en,Wce))+up2(dw3x3(conv1x1(de,Wcd)))))
// B=4, C=256, H=64, W=64. Inputs fp32 (runtime-detected), output fp32.

typedef unsigned short u16;
typedef unsigned int u32;
typedef float v2f __attribute__((ext_vector_type(2)));

#define NB 4
#define NC 256
#define NH 64
#define NW 64
#define NH2 128
#define NW2 128

// fp32 weights in ws (shared by both paths)
#define OFF_WG   0
#define OFF_BG   256
#define OFF_WCE  272
#define OFF_BCE  6672
#define OFF_WCD  6704
#define OFF_WDW  13104
#define OFF_BDW  13330
#define OFF_FLAG 13356    // 1.0f = fp32 inputs, 0.0f = bf16 inputs

// ---- optimized (full-batch) layout, floats ----
#define OFF_GATE 16384    // 4*4096 fp32                    -> 32768
#define OFF_KB   32768    // 4*4096*100 u16 (819200 fl)     -> 851968
#define OFF_ENC  851968   // 4*25*16384 fp32                -> 2490368
#define OFF_DEC  2490368  // 4*25*4096 fp32                 -> 2899968
#define OFF_DET  851968   // 4*68*68*256 u16, aliases dead ENC+DEC after o4 -> 3219456
#define OFF_P1   851968   // o1a partials: 2*4*26*4096 fl in ENC area,
                          // consumed by o1b BEFORE o3 writes ENC.
#define FULL_NEED_BYTES 12877824ull

// ---- naive (per-batch) layout, floats ----
#define NGATE 16384
#define NDEC  20480
#define NENC  122880
#define NKBF  532480      // -> end 942080 (3.77 MB)

__device__ __forceinline__ float bf2f(u16 u){ return __uint_as_float(((u32)u) << 16); }
__device__ __forceinline__ u16 f2bf(float f){
  u32 x = __float_as_uint(f);
  return (u16)((x + 0x7fffu + ((x >> 16) & 1u)) >> 16);  // RNE (finite)
}
__device__ __forceinline__ float ldin(const void* p, int i, bool f32){
  return f32 ? ((const float*)p)[i] : bf2f(((const u16*)p)[i]);
}

// dtype detector on `de` (~N(0,1)): bf16 exp in [0x70,0x82] nearly always;
// fp32 low-mantissa u16s ~uniform (~7% hit).
__global__ __launch_bounds__(256) void k_detect(const void* de_raw, float* ws){
  __shared__ int cnt;
  if (threadIdx.x == 0) cnt = 0;
  __syncthreads();
  int c = 0;
#pragma unroll
  for (int s = 0; s < 2; s++) {
    int i = (threadIdx.x + s * 256) * 2;
    u16 u = ((const u16*)de_raw)[i];
    int e = (u >> 7) & 0xff;
    if (e >= 0x70 && e <= 0x82) c++;
  }
  atomicAdd(&cnt, c);
  __syncthreads();
  if (threadIdx.x == 0) ws[OFF_FLAG] = (cnt < 256) ? 1.0f : 0.0f;
}

__global__ __launch_bounds__(256) void k_prep(const void* Wg, const void* bg,
    const void* Wce, const void* bce, const void* Wcd, const void* Wdw, const void* bdw,
    float* ws){
  bool f = ws[OFF_FLAG] != 0.f;
  int i = threadIdx.x + blockIdx.x * 256;
  if (i < 6400) {
    ws[OFF_WCE + i] = ldin(Wce, i, f);
    ws[OFF_WCD + i] = ldin(Wcd, i, f);
    if (i < 256) ws[OFF_WG + i] = ldin(Wg, i, f);
    if (i < 1)   ws[OFF_BG + i] = ldin(bg, i, f);
    if (i < 25)  ws[OFF_BCE + i] = ldin(bce, i, f);
    if (i < 225) ws[OFF_WDW + i] = ldin(Wdw, i, f);
    if (i < 25)  ws[OFF_BDW + i] = ldin(bdw, i, f);
  }
}

// ================= optimized path =================

// o1a: partial DEC/GATE over a 128-channel chunk.
// grid = B*64*2 (512): b = bi>>7, rem&127 -> h = rem>>1, chunk = rem&1.
// block 256 = 4 waves; wave g covers channels chunk*128 + g*32 .. +31.
// Partials (raw, no bias/sigmoid) -> OFF_P1[(chunk*NB+b)*26+o][h][w].
__global__ __launch_bounds__(256) void o1a_dec_gate(const void* de, float* ws){
  __shared__ float red[4][26][64];
  bool f = ws[OFF_FLAG] != 0.f;
  int b = blockIdx.x >> 7;
  int rem = blockIdx.x & 127;
  int h = rem >> 1;
  int chunk = rem & 1;
  int g = threadIdx.x >> 6;
  int w = threadIdx.x & 63;
  int c0 = __builtin_amdgcn_readfirstlane(chunk * 128 + g * 32);
  float acc[26];
#pragma unroll
  for (int o = 0; o < 26; o++) acc[o] = 0.f;
  int idx = ((b * NC + c0) * NH + h) * NW + w;
  for (int ci = 0; ci < 32; ci += 8) {
    float v0 = ldin(de, idx,            f);
    float v1 = ldin(de, idx + 1 * 4096, f);
    float v2 = ldin(de, idx + 2 * 4096, f);
    float v3 = ldin(de, idx + 3 * 4096, f);
    float v4 = ldin(de, idx + 4 * 4096, f);
    float v5 = ldin(de, idx + 5 * 4096, f);
    float v6 = ldin(de, idx + 6 * 4096, f);
    float v7 = ldin(de, idx + 7 * 4096, f);
    idx += 8 * 4096;
    int c = c0 + ci;
    acc[25] += ws[OFF_WG + c] * v0 + ws[OFF_WG + c + 1] * v1
             + ws[OFF_WG + c + 2] * v2 + ws[OFF_WG + c + 3] * v3
             + ws[OFF_WG + c + 4] * v4 + ws[OFF_WG + c + 5] * v5
             + ws[OFF_WG + c + 6] * v6 + ws[OFF_WG + c + 7] * v7;
#pragma unroll
    for (int k = 0; k < 25; k++) {
      const float* wk = ws + OFF_WCD + k * 256 + c;
      acc[k] += wk[0] * v0 + wk[1] * v1 + wk[2] * v2 + wk[3] * v3
              + wk[4] * v4 + wk[5] * v5 + wk[6] * v6 + wk[7] * v7;
    }
  }
#pragma unroll
  for (int o = 0; o < 26; o++) red[g][o][w] = acc[o];
  __syncthreads();
  for (int item = threadIdx.x; item < 26 * 64; item += 256) {
    int o = item >> 6; int ww = item & 63;
    float s = red[0][o][ww] + red[1][o][ww] + red[2][o][ww] + red[3][o][ww];
    ws[OFF_P1 + (((chunk * NB + b) * 26 + o) << 12) + (h << 6) + ww] = s;
  }
}

// o1b: DEC = p0+p1; GATE = sigmoid(p0+p1+bg). grid = 1664*256 = NB*26*4096.
__global__ __launch_bounds__(256) void o1b_reduce(float* ws){
  int i = blockIdx.x * 256 + threadIdx.x;
  int b = i / (26 * 4096);
  int r = i - b * 26 * 4096;
  int o = r >> 12;
  int pix = r & 4095;
  float s = ws[OFF_P1 + (((0 * NB + b) * 26 + o) << 12) + pix]
          + ws[OFF_P1 + (((1 * NB + b) * 26 + o) << 12) + pix];
  if (o < 25)
    ws[OFF_DEC + ((b * 25 + o) << 12) + pix] = s;
  else {
    float z = s + ws[OFF_BG];
    ws[OFF_GATE + (b << 12) + pix] = 1.f / (1.f + __expf(-z));
  }
}

// DET[b][p][q][c] = de[b][c][p-2][q-2] (0 outside), bf16. Runs AFTER o4 (aliases ENC+DEC).
// grid = B*68*4 (1088): b = bi/272, r = bi%272, p = r>>2, c-chunk = (r&3)*64.
// Coalesced de reads (lanes across w) -> LDS transpose tile[64][65] (stride-65,
// 2-way = free) -> coalesced DET writes (lanes across c).
__global__ __launch_bounds__(256) void o2_det(const void* de, float* ws){
  __shared__ float tile[64][65];
  bool f = ws[OFF_FLAG] != 0.f;
  u16* det = (u16*)(ws + OFF_DET);
  int b = blockIdx.x / 272;
  int r = blockIdx.x % 272;
  int p = r >> 2;
  int c0 = (r & 3) << 6;
  int h = p - 2;
  bool hv = (h >= 0 && h < NH);
  for (int item = threadIdx.x; item < 64 * 64; item += 256) {
    int cl = item >> 6, w = item & 63;
    float v = hv ? ldin(de, ((b * NC + c0 + cl) * NH + h) * NW + w, f) : 0.f;
    tile[w][cl] = v;
  }
  __syncthreads();
  u16* dst = det + ((b * 68 + p) * 68) * NC + c0;
  for (int item = threadIdx.x; item < 68 * 64; item += 256) {
    int q = item >> 6, cl = item & 63;
    int w = q - 2;
    float v = (w >= 0 && w < NW) ? tile[w][cl] : 0.f;
    dst[q * NC + cl] = f2bf(v);
  }
}

// ENC = conv1x1(en, W_ce)+b_ce.
// grid = B*128*2 (1024): b = bi>>8, rem&255 -> y = rem>>1, xs = (rem&1)*64.
// block 256 = 4 waves; wave g covers channels g*64..+63, lanes = 64 x.
// Channel loop unrolled x8 with independent temps -> 8 loads in flight.
__global__ __launch_bounds__(256) void o3_enc(const void* en, float* ws){
  __shared__ float red[4][25][64];
  bool f = ws[OFF_FLAG] != 0.f;
  int b = blockIdx.x >> 8;
  int rem = blockIdx.x & 255;
  int y = rem >> 1;
  int xs = (rem & 1) << 6;
  int g = threadIdx.x >> 6;
  int xl = threadIdx.x & 63;
  int c0 = __builtin_amdgcn_readfirstlane(g * 64);
  float acc[25];
#pragma unroll
  for (int k = 0; k < 25; k++) acc[k] = 0.f;
  int idx = ((b * NC + c0) * NH2 + y) * NW2 + xs + xl;
  for (int ci = 0; ci < 64; ci += 8) {
    float v0 = ldin(en, idx,             f);
    float v1 = ldin(en, idx + 1 * 16384, f);
    float v2 = ldin(en, idx + 2 * 16384, f);
    float v3 = ldin(en, idx + 3 * 16384, f);
    float v4 = ldin(en, idx + 4 * 16384, f);
    float v5 = ldin(en, idx + 5 * 16384, f);
    float v6 = ldin(en, idx + 6 * 16384, f);
    float v7 = ldin(en, idx + 7 * 16384, f);
    idx += 8 * 16384;
    int c = c0 + ci;
#pragma unroll
    for (int k = 0; k < 25; k++) {
      const float* wk = ws + OFF_WCE + k * 256 + c;
      acc[k] += wk[0] * v0 + wk[1] * v1 + wk[2] * v2 + wk[3] * v3
              + wk[4] * v4 + wk[5] * v5 + wk[6] * v6 + wk[7] * v7;
    }
  }
#pragma unroll
  for (int k = 0; k < 25; k++) red[g][k][xl] = acc[k];
  __syncthreads();
  for (int item = threadIdx.x; item < 25 * 64; item += 256) {
    int k = item >> 6; int xx = item & 63;
    float s = red[0][k][xx] + red[1][k][xx] + red[2][k][xx] + red[3][k][xx]
            + ws[OFF_BCE + k];
    ws[OFF_ENC + ((b * 25 + k) * NH2 + y) * NW2 + xs + xx] = s;
  }
}

// raw = dw3x3(ENC)+b + up2(dw3x3(DEC)+b); softmax over 25 -> KB bf16 [b][h][w][tap*4+st]
// grid = B*128*2 (1024): each block = one output row y, 64-pixel x-strip.
// 256 threads = 4 tap-groups x 64 pixels; group tg computes taps k=tg,tg+4,...
// Partial raw values go to LDS red[25][64]; wave 0 does softmax straight from
// LDS (no 25-register array -> no scratch spill).
__global__ __launch_bounds__(256) void o4_kernels(float* ws){
  __shared__ float red[25][64];
  int b = blockIdx.x >> 8;
  int rem = blockIdx.x & 255;
  int y = rem >> 1;
  int xs = (rem & 1) << 6;
  int tg = __builtin_amdgcn_readfirstlane(threadIdx.x >> 6);
  int xl = threadIdx.x & 63;
  int x = xs + xl;
  int h = y >> 1, w = x >> 1;
  const float* enc = ws + OFF_ENC + (b * 25) * NH2 * NW2;
  const float* dec = ws + OFF_DEC + (b * 25) * NH * NW;

  for (int k = tg; k < 25; k += 4) {
    float s = 2.f * ws[OFF_BDW + k];
#pragma unroll
    for (int u = 0; u < 3; u++) {
      int yy = y + u - 1, hh = h + u - 1;
      bool yok = (yy >= 0 && yy < NH2);
      bool hok = (hh >= 0 && hh < NH);
#pragma unroll
      for (int v = 0; v < 3; v++) {
        int xx = x + v - 1, w2 = w + v - 1;
        float wd = ws[OFF_WDW + k * 9 + u * 3 + v];
        if (yok && xx >= 0 && xx < NW2)
          s += enc[(k * NH2 + yy) * NW2 + xx] * wd;
        if (hok && w2 >= 0 && w2 < NW)
          s += dec[(k * NH + hh) * NW + w2] * wd;
      }
    }
    red[k][xl] = s;
  }
  __syncthreads();

  if (threadIdx.x < 64) {
    int t = threadIdx.x;
    int xp = xs + t;
    float m = -1e30f;
#pragma unroll
    for (int k = 0; k < 25; k++) m = fmaxf(m, red[k][t]);
    float sum = 0.f;
#pragma unroll
    for (int k = 0; k < 25; k++) {
      float e = __expf(red[k][t] - m);
      red[k][t] = e;
      sum += e;
    }
    float inv = 1.f / sum;
    int st = ((y & 1) << 1) + (xp & 1);
    int wp = xp >> 1;
    u16* kbu = (u16*)(ws + OFF_KB);
    u16* dst = kbu + ((b * NH + h) * NW + wp) * 100 + st;
#pragma unroll
    for (int k = 0; k < 25; k++) dst[k * 4] = f2bf(red[k][t] * inv);
  }
}

// Channel-major carafe + gate blend, fp32 out.
// grid = B*64*4*2 (2048), block 256 (4 waves), split by output row s.
// Swizzle: xcd = bi&7, slot = bi>>3, s = slot&1, pid = ((slot>>1)<<3)|xcd.
// Phase 1 (r11): dy-outer, one acc block for all 4 wu of the wave, 8 unique
// DET columns loaded once per dy (j=i+dx), v_pk_fma_f32 with op_sel k-broadcast.
__global__ __launch_bounds__(256) void o5_final(const void* en, float* ws, float* out){
  __shared__ u16 stag[32][260];
  bool f = ws[OFF_FLAG] != 0.f;
  const u16* det = (const u16*)(ws + OFF_DET);
  const u16* kbu = (const u16*)(ws + OFF_KB);
  const float* gate = ws + OFF_GATE;

  int bi = blockIdx.x;
  int xcd = bi & 7;
  int slot = bi >> 3;
  int s = slot & 1;
  int pid = ((slot >> 1) << 3) | xcd;
  int b = pid >> 8;
  int rem = pid & 255;
  int h = rem >> 2;
  int w0b = (rem & 3) * 16;
  int wave = threadIdx.x >> 6;
  int lane = threadIdx.x & 63;
  int c4 = lane * 4;

  int wu0 = __builtin_amdgcn_readfirstlane(w0b + wave * 4);
  const u16* kp0 = kbu + ((b * NH + h) * NW + wu0) * 100 + s * 2;

  // acc[i][st][cpair]: i = wu0+i pixel, st = output col parity, cpair = (c0c1)/(c2c3)
  v2f acc[4][2][2];
#pragma unroll
  for (int i = 0; i < 4; i++)
#pragma unroll
    for (int t = 0; t < 2; t++)
#pragma unroll
      for (int p = 0; p < 2; p++) { acc[i][t][p].x = 0.f; acc[i][t][p].y = 0.f; }

#pragma unroll
  for (int dy = 0; dy < 5; dy++) {
    const u16* dp = det + (((b * 68 + h + dy) * 68 + wu0) * NC) + c4;
    // 8 unique DET columns for this dy (j = i+dx, i<4, dx<5)
    u32 wlo[8], whi[8];
#pragma unroll
    for (int j = 0; j < 8; j++) {
      uint2 dv = *(const uint2*)(dp + j * NC);
      wlo[j] = dv.x; whi[j] = dv.y;
    }
#pragma unroll
    for (int i = 0; i < 4; i++) {
#pragma unroll
      for (int dx = 0; dx < 5; dx++) {
        int j = i + dx;
        u32 kk = *(const u32*)(kp0 + i * 100 + (dy * 5 + dx) * 4);  // uniform -> s_load
        v2f kp2, vA, vB;
        kp2.x = __uint_as_float(kk << 16);            // k0 (st s*2)
        kp2.y = __uint_as_float(kk & 0xffff0000u);    // k1 (st s*2+1)
        vA.x = __uint_as_float(wlo[j] << 16);         // c4+0
        vA.y = __uint_as_float(wlo[j] & 0xffff0000u); // c4+1
        vB.x = __uint_as_float(whi[j] << 16);         // c4+2
        vB.y = __uint_as_float(whi[j] & 0xffff0000u); // c4+3
        // st0: broadcast kp2.lo ; st1: broadcast kp2.hi
        asm("v_pk_fma_f32 %0, %1, %2, %0 op_sel:[0,0,0] op_sel_hi:[0,1,1]"
            : "+v"(acc[i][0][0]) : "v"(kp2), "v"(vA));
        asm("v_pk_fma_f32 %0, %1, %2, %0 op_sel:[0,0,0] op_sel_hi:[0,1,1]"
            : "+v"(acc[i][0][1]) : "v"(kp2), "v"(vB));
        asm("v_pk_fma_f32 %0, %1, %2, %0 op_sel:[1,0,0] op_sel_hi:[1,1,1]"
            : "+v"(acc[i][1][0]) : "v"(kp2), "v"(vA));
        asm("v_pk_fma_f32 %0, %1, %2, %0 op_sel:[1,0,0] op_sel_hi:[1,1,1]"
            : "+v"(acc[i][1][1]) : "v"(kp2), "v"(vB));
      }
    }
  }

#pragma unroll
  for (int i = 0; i < 4; i++) {
    int xl = (wave * 4 + i) * 2;
#pragma unroll
    for (int t = 0; t < 2; t++) {
      ushort4 pv;
      pv.x = f2bf(acc[i][t][0].x); pv.y = f2bf(acc[i][t][0].y);
      pv.z = f2bf(acc[i][t][1].x); pv.w = f2bf(acc[i][t][1].y);
      *(ushort4*)&stag[xl + t][c4] = pv;
    }
  }
  __syncthreads();

  int xp = threadIdx.x & 31;
  int cb = (threadIdx.x >> 5) * 2;
  int x = w0b * 2 + xp;
  int wpix = w0b + (xp >> 1);
  int y = 2 * h + s;
  float g = gate[(b * NH + h) * NW + wpix];
  float gi = 1.f - g;
#pragma unroll
  for (int pass = 0; pass < 16; pass++) {
    int c = cb + pass * 16;
    u32 rr = *(const u32*)&stag[xp][c];
    float cr0 = bf2f((u16)(rr & 0xffffu));
    float cr1 = bf2f((u16)(rr >> 16));
    int eidx = ((b * NC + c) * NH2 + y) * NW2 + x;
    float e0 = ldin(en, eidx, f);
    float e1 = ldin(en, eidx + NH2 * NW2, f);
    __builtin_nontemporal_store(g * e0 + gi * cr0, &out[eidx]);
    __builtin_nontemporal_store(g * e1 + gi * cr1, &out[eidx + NH2 * NW2]);
  }
}

// ================= naive fallback path (verified round 6) =================

__global__ __launch_bounds__(256) void kA_gate(const void* de, float* ws, int b){
  bool f = ws[OFF_FLAG] != 0.f;
  int idx = blockIdx.x * 256 + threadIdx.x;
  int h = idx >> 6, w = idx & 63;
  float s = ws[OFF_BG];
  for (int c = 0; c < NC; c++)
    s += ldin(de, ((b * NC + c) * NH + h) * NW + w, f) * ws[OFF_WG + c];
  ws[NGATE + idx] = 1.f / (1.f + __expf(-s));
}

__global__ __launch_bounds__(256) void kB_dec(const void* de, float* ws, int b){
  bool f = ws[OFF_FLAG] != 0.f;
  int idx = blockIdx.x * 256 + threadIdx.x;
  int h = idx >> 6, w = idx & 63;
  float acc[25];
#pragma unroll
  for (int k = 0; k < 25; k++) acc[k] = 0.f;
  for (int c = 0; c < NC; c++) {
    float v = ldin(de, ((b * NC + c) * NH + h) * NW + w, f);
#pragma unroll
    for (int k = 0; k < 25; k++) acc[k] += v * ws[OFF_WCD + k * 256 + c];
  }
#pragma unroll
  for (int k = 0; k < 25; k++)
    ws[NDEC + (k * NH + h) * NW + w] = acc[k];
}

__global__ __launch_bounds__(256) void kC_enc(const void* en, float* ws, int b){
  bool f = ws[OFF_FLAG] != 0.f;
  int idx = blockIdx.x * 256 + threadIdx.x;
  int y = idx >> 7, x = idx & 127;
  float acc[25];
#pragma unroll
  for (int k = 0; k < 25; k++) acc[k] = 0.f;
  for (int c = 0; c < NC; c++) {
    float v = ldin(en, ((b * NC + c) * NH2 + y) * NW2 + x, f);
#pragma unroll
    for (int k = 0; k < 25; k++) acc[k] += v * ws[OFF_WCE + k * 256 + c];
  }
#pragma unroll
  for (int k = 0; k < 25; k++)
    ws[NENC + (k * NH2 + y) * NW2 + x] = acc[k] + ws[OFF_BCE + k];
}

__global__ __launch_bounds__(256) void kD_kern(float* ws){
  int idx = blockIdx.x * 256 + threadIdx.x;
  int y = idx >> 7, x = idx & 127;
  int h = y >> 1, w = x >> 1;
  float raw[25];
#pragma unroll
  for (int k = 0; k < 25; k++) {
    float s = 2.f * ws[OFF_BDW + k];
#pragma unroll
    for (int u = 0; u < 3; u++) {
      int yy = y + u - 1, hh = h + u - 1;
#pragma unroll
      for (int v = 0; v < 3; v++) {
        int xx = x + v - 1, ww = w + v - 1;
        float wd = ws[OFF_WDW + k * 9 + u * 3 + v];
        if (yy >= 0 && yy < NH2 && xx >= 0 && xx < NW2)
          s += ws[NENC + (k * NH2 + yy) * NW2 + xx] * wd;
        if (hh >= 0 && hh < NH && ww >= 0 && ww < NW)
          s += ws[NDEC + (k * NH + hh) * NW + ww] * wd;
      }
    }
    raw[k] = s;
  }
  float m = raw[0];
#pragma unroll
  for (int k = 1; k < 25; k++) m = fmaxf(m, raw[k]);
  float sum = 0.f;
#pragma unroll
  for (int k = 0; k < 25; k++) { raw[k] = __expf(raw[k] - m); sum += raw[k]; }
  float inv = 1.f / sum;
  float* dst = ws + NKBF + idx * 25;
#pragma unroll
  for (int k = 0; k < 25; k++) dst[k] = raw[k] * inv;
}

__global__ __launch_bounds__(256) void kE_out(const void* en, const void* de,
    const float* ws, float* out, int b){
  bool f = ws[OFF_FLAG] != 0.f;
  int idx = blockIdx.x * 256 + threadIdx.x;
  int c = idx >> 14;
  int y = (idx >> 7) & 127;
  int x = idx & 127;
  int h = y >> 1, w = x >> 1;
  const float* kb = ws + NKBF + (y * NW2 + x) * 25;
  float acc = 0.f;
#pragma unroll
  for (int dy = 0; dy < 5; dy++) {
    int hh = h + dy - 2;
    if (hh < 0 || hh >= NH) continue;
#pragma unroll
    for (int dx = 0; dx < 5; dx++) {
      int ww = w + dx - 2;
      if (ww < 0 || ww >= NW) continue;
      acc += ldin(de, ((b * NC + c) * NH + hh) * NW + ww, f) * kb[dy * 5 + dx];
    }
  }
  float g = ws[NGATE + h * NW + w];
  float e = ldin(en, ((b * NC + c) * NH2 + y) * NW2 + x, f);
  out[((b * NC + c) * NH2 + y) * NW2 + x] = g * e + (1.f - g) * acc;
}

// resolve input by flat element count (robust to permutation); fallback positional
static const void* find_by_size(void* const* d_in, const int* in_sizes, int n_in,
                                int want, int skip, const void* fb){
  int seen = 0;
  for (int i = 0; i < n_in; i++)
    if (in_sizes[i] == want) {
      if (seen == skip) return d_in[i];
      seen++;
    }
  return fb;
}

extern "C" void kernel_launch(void* const* d_in, const int* in_sizes, int n_in,
                              void* d_out, int out_size, void* d_ws, size_t ws_size,
                              hipStream_t stream) {
  (void)out_size;
  const void* en  = find_by_size(d_in, in_sizes, n_in, 4*256*128*128, 0, d_in[0]);
  const void* de  = find_by_size(d_in, in_sizes, n_in, 4*256*64*64,   0, d_in[1]);
  const void* Wg  = find_by_size(d_in, in_sizes, n_in, 256,           0, d_in[2]);
  const void* bg  = find_by_size(d_in, in_sizes, n_in, 1,             0, d_in[3]);
  const void* Wce = find_by_size(d_in, in_sizes, n_in, 6400,          0, d_in[4]);
  const void* bce = find_by_size(d_in, in_sizes, n_in, 25,            0, d_in[5]);
  const void* Wcd = find_by_size(d_in, in_sizes, n_in, 6400,          1, d_in[6]);
  const void* Wdw = find_by_size(d_in, in_sizes, n_in, 225,           0, d_in[7]);
  const void* bdw = find_by_size(d_in, in_sizes, n_in, 25,            1, d_in[8]);
  float* ws = (float*)d_ws;
  float* out = (float*)d_out;

  hipLaunchKernelGGL(k_detect, dim3(1), dim3(256), 0, stream, de, ws);
  hipLaunchKernelGGL(k_prep, dim3(25), dim3(256), 0, stream,
                     Wg, bg, Wce, bce, Wcd, Wdw, bdw, ws);

  if (ws_size >= FULL_NEED_BYTES) {
    hipLaunchKernelGGL(o1a_dec_gate, dim3(NB * NH * 2),     dim3(256), 0, stream, de, ws);
    hipLaunchKernelGGL(o1b_reduce,   dim3(1664),            dim3(256), 0, stream, ws);
    hipLaunchKernelGGL(o3_enc,       dim3(NB * NH2 * 2),    dim3(256), 0, stream, en, ws);
    hipLaunchKernelGGL(o4_kernels,   dim3(NB * NH2 * 2),    dim3(256), 0, stream, ws);
    hipLaunchKernelGGL(o2_det,       dim3(NB * 68 * 4),     dim3(256), 0, stream, de, ws);
    hipLaunchKernelGGL(o5_final,     dim3(NB * NH * 4 * 2), dim3(256), 0, stream, en, ws, out);
  } else {
    for (int b = 0; b < NB; b++) {
      hipLaunchKernelGGL(kA_gate, dim3(16),    dim3(256), 0, stream, de, ws, b);
      hipLaunchKernelGGL(kB_dec,  dim3(16),    dim3(256), 0, stream, de, ws, b);
      hipLaunchKernelGGL(kC_enc,  dim3(64),    dim3(256), 0, stream, en, ws, b);
      hipLaunchKernelGGL(kD_kern, dim3(64),    dim3(256), 0, stream, ws);
      hipLaunchKernelGGL(kE_out,  dim3(16384), dim3(256), 0, stream, en, de, ws, out, b);
    }
  }
}

// Round 5
// 239.917 us; speedup vs baseline: 1.5859x; 1.0000x over previous
//
#include <hip/hip_runtime.h>

// FADE-Lite round 12: o3 pk-fma x-pair rewrite + launch diet.
// r4 counters: top-5 all fillBufferAligned (256 MiB ws poison) -> all our
// kernels < 41us, ws is huge. (1) o3: each lane owns 2 adjacent x (float2
// loads, v2f MACs -> v_pk_fma_f32), VALU issue halved for same traffic;
// (2) P1 partials moved to dedicated region (no ENC alias) so o1b's reduce
// fuses into o3's tail; (3) k_detect merged into k_prep (each block votes
// locally). 8 launches -> 6. Everything else identical to verified round 11.
//
// out = gate*en + (1-gate)*CARAFE(de, softmax_k(dw3x3(conv1x1(en,Wce))+up2(dw3x3(conv1x1(de,Wcd)))))
// B=4, C=256, H=64, W=64. Inputs fp32 (runtime-detected), output fp32.

typedef unsigned short u16;
typedef unsigned int u32;
typedef float v2f __attribute__((ext_vector_type(2)));

#define NB 4
#define NC 256
#define NH 64
#define NW 64
#define NH2 128
#define NW2 128

// fp32 weights in ws (shared by both paths)
#define OFF_WG   0
#define OFF_BG   256
#define OFF_WCE  272
#define OFF_BCE  6672
#define OFF_WCD  6704
#define OFF_WDW  13104
#define OFF_BDW  13330
#define OFF_FLAG 13356    // 1.0f = fp32 inputs, 0.0f = bf16 inputs

// ---- optimized (full-batch) layout, floats ----
#define OFF_GATE 16384    // 4*4096 fp32                    -> 32768
#define OFF_KB   32768    // 4*4096*100 u16 (819200 fl)     -> 851968
#define OFF_ENC  851968   // 4*25*16384 fp32                -> 2490368
#define OFF_DEC  2490368  // 4*25*4096 fp32                 -> 2899968
#define OFF_DET  851968   // 4*68*68*256 u16, aliases dead ENC+DEC after o4 -> 3219456
#define OFF_P1   3219456  // o1a partials: 2*4*26*4096 fl (dedicated) -> 4071424
#define FULL_NEED_BYTES 16285696ull

// ---- naive (per-batch) layout, floats ----
#define NGATE 16384
#define NDEC  20480
#define NENC  122880
#define NKBF  532480      // -> end 942080 (3.77 MB)

__device__ __forceinline__ float bf2f(u16 u){ return __uint_as_float(((u32)u) << 16); }
__device__ __forceinline__ u16 f2bf(float f){
  u32 x = __float_as_uint(f);
  return (u16)((x + 0x7fffu + ((x >> 16) & 1u)) >> 16);  // RNE (finite)
}
__device__ __forceinline__ float ldin(const void* p, int i, bool f32){
  return f32 ? ((const float*)p)[i] : bf2f(((const u16*)p)[i]);
}
// paired load: elements i, i+1 (i even for alignment)
__device__ __forceinline__ v2f ldin2(const void* p, int i, bool f32){
  v2f r;
  if (f32) {
    float2 t = *(const float2*)((const float*)p + i);
    r.x = t.x; r.y = t.y;
  } else {
    u32 u = *(const u32*)((const u16*)p + i);
    r.x = bf2f((u16)(u & 0xffffu)); r.y = bf2f((u16)(u >> 16));
  }
  return r;
}

// k_prep with fused dtype detect: every block votes on 512 samples of `de`
// (identical data -> identical result); block 0 publishes the flag for later
// kernels. bf16 exp in [0x70,0x82] nearly always; fp32 low-u16s ~7% hit.
__global__ __launch_bounds__(256) void k_prep(const void* de_raw,
    const void* Wg, const void* bg, const void* Wce, const void* bce,
    const void* Wcd, const void* Wdw, const void* bdw, float* ws){
  __shared__ int cnt;
  if (threadIdx.x == 0) cnt = 0;
  __syncthreads();
  int c = 0;
#pragma unroll
  for (int s = 0; s < 2; s++) {
    int i = (threadIdx.x + s * 256) * 2;
    u16 u = ((const u16*)de_raw)[i];
    int e = (u >> 7) & 0xff;
    if (e >= 0x70 && e <= 0x82) c++;
  }
  atomicAdd(&cnt, c);
  __syncthreads();
  bool f = cnt < 256;
  if (blockIdx.x == 0 && threadIdx.x == 0) ws[OFF_FLAG] = f ? 1.0f : 0.0f;
  int i = threadIdx.x + blockIdx.x * 256;
  if (i < 6400) {
    ws[OFF_WCE + i] = ldin(Wce, i, f);
    ws[OFF_WCD + i] = ldin(Wcd, i, f);
    if (i < 256) ws[OFF_WG + i] = ldin(Wg, i, f);
    if (i < 1)   ws[OFF_BG + i] = ldin(bg, i, f);
    if (i < 25)  ws[OFF_BCE + i] = ldin(bce, i, f);
    if (i < 225) ws[OFF_WDW + i] = ldin(Wdw, i, f);
    if (i < 25)  ws[OFF_BDW + i] = ldin(bdw, i, f);
  }
}

// ================= optimized path =================

// o1a: partial DEC/GATE over a 128-channel chunk.
// grid = B*64*2 (512): b = bi>>7, rem&127 -> h = rem>>1, chunk = rem&1.
// block 256 = 4 waves; wave g covers channels chunk*128 + g*32 .. +31.
// Partials (raw, no bias/sigmoid) -> OFF_P1[(chunk*NB+b)*26+o][h][w].
__global__ __launch_bounds__(256) void o1a_dec_gate(const void* de, float* ws){
  __shared__ float red[4][26][64];
  bool f = ws[OFF_FLAG] != 0.f;
  int b = blockIdx.x >> 7;
  int rem = blockIdx.x & 127;
  int h = rem >> 1;
  int chunk = rem & 1;
  int g = threadIdx.x >> 6;
  int w = threadIdx.x & 63;
  int c0 = __builtin_amdgcn_readfirstlane(chunk * 128 + g * 32);
  float acc[26];
#pragma unroll
  for (int o = 0; o < 26; o++) acc[o] = 0.f;
  int idx = ((b * NC + c0) * NH + h) * NW + w;
  for (int ci = 0; ci < 32; ci += 8) {
    float v0 = ldin(de, idx,            f);
    float v1 = ldin(de, idx + 1 * 4096, f);
    float v2 = ldin(de, idx + 2 * 4096, f);
    float v3 = ldin(de, idx + 3 * 4096, f);
    float v4 = ldin(de, idx + 4 * 4096, f);
    float v5 = ldin(de, idx + 5 * 4096, f);
    float v6 = ldin(de, idx + 6 * 4096, f);
    float v7 = ldin(de, idx + 7 * 4096, f);
    idx += 8 * 4096;
    int c = c0 + ci;
    acc[25] += ws[OFF_WG + c] * v0 + ws[OFF_WG + c + 1] * v1
             + ws[OFF_WG + c + 2] * v2 + ws[OFF_WG + c + 3] * v3
             + ws[OFF_WG + c + 4] * v4 + ws[OFF_WG + c + 5] * v5
             + ws[OFF_WG + c + 6] * v6 + ws[OFF_WG + c + 7] * v7;
#pragma unroll
    for (int k = 0; k < 25; k++) {
      const float* wk = ws + OFF_WCD + k * 256 + c;
      acc[k] += wk[0] * v0 + wk[1] * v1 + wk[2] * v2 + wk[3] * v3
              + wk[4] * v4 + wk[5] * v5 + wk[6] * v6 + wk[7] * v7;
    }
  }
#pragma unroll
  for (int o = 0; o < 26; o++) red[g][o][w] = acc[o];
  __syncthreads();
  for (int item = threadIdx.x; item < 26 * 64; item += 256) {
    int o = item >> 6; int ww = item & 63;
    float s = red[0][o][ww] + red[1][o][ww] + red[2][o][ww] + red[3][o][ww];
    ws[OFF_P1 + (((chunk * NB + b) * 26 + o) << 12) + (h << 6) + ww] = s;
  }
}

// DET[b][p][q][c] = de[b][c][p-2][q-2] (0 outside), bf16. Runs AFTER o4 (aliases ENC+DEC).
// grid = B*68*4 (1088): b = bi/272, r = bi%272, p = r>>2, c-chunk = (r&3)*64.
// Coalesced de reads (lanes across w) -> LDS transpose tile[64][65] ->
// coalesced DET writes (lanes across c).
__global__ __launch_bounds__(256) void o2_det(const void* de, float* ws){
  __shared__ float tile[64][65];
  bool f = ws[OFF_FLAG] != 0.f;
  u16* det = (u16*)(ws + OFF_DET);
  int b = blockIdx.x / 272;
  int r = blockIdx.x % 272;
  int p = r >> 2;
  int c0 = (r & 3) << 6;
  int h = p - 2;
  bool hv = (h >= 0 && h < NH);
  for (int item = threadIdx.x; item < 64 * 64; item += 256) {
    int cl = item >> 6, w = item & 63;
    float v = hv ? ldin(de, ((b * NC + c0 + cl) * NH + h) * NW + w, f) : 0.f;
    tile[w][cl] = v;
  }
  __syncthreads();
  u16* dst = det + ((b * 68 + p) * 68) * NC + c0;
  for (int item = threadIdx.x; item < 68 * 64; item += 256) {
    int q = item >> 6, cl = item & 63;
    int w = q - 2;
    float v = (w >= 0 && w < NW) ? tile[w][cl] : 0.f;
    dst[q * NC + cl] = f2bf(v);
  }
}

// ENC = conv1x1(en, W_ce)+b_ce, x-paired pk-fma version.
// grid = B*128 (512): b = bi>>7, y = bi&127 (full row per block).
// block 256 = 4 c-groups x 64 lanes; lane owns x = 2*xl, 2*xl+1 (float2 loads,
// v2f MACs -> v_pk_fma_f32). Channel loop unrolled x8 = 8 loads in flight.
// Tail: fused o1b reduce (DEC/GATE from P1) - 832 elements per block.
__global__ __launch_bounds__(256) void o3_enc(const void* en, float* ws){
  __shared__ v2f red[4][25][64];
  bool f = ws[OFF_FLAG] != 0.f;
  int b = blockIdx.x >> 7;
  int y = blockIdx.x & 127;
  int g = threadIdx.x >> 6;
  int xl = threadIdx.x & 63;
  int c0 = __builtin_amdgcn_readfirstlane(g * 64);
  v2f acc[25];
#pragma unroll
  for (int k = 0; k < 25; k++) { acc[k].x = 0.f; acc[k].y = 0.f; }
  int idx = ((b * NC + c0) * NH2 + y) * NW2 + 2 * xl;
  for (int ci = 0; ci < 64; ci += 8) {
    v2f v0 = ldin2(en, idx,             f);
    v2f v1 = ldin2(en, idx + 1 * 16384, f);
    v2f v2 = ldin2(en, idx + 2 * 16384, f);
    v2f v3 = ldin2(en, idx + 3 * 16384, f);
    v2f v4 = ldin2(en, idx + 4 * 16384, f);
    v2f v5 = ldin2(en, idx + 5 * 16384, f);
    v2f v6 = ldin2(en, idx + 6 * 16384, f);
    v2f v7 = ldin2(en, idx + 7 * 16384, f);
    idx += 8 * 16384;
    int c = c0 + ci;
#pragma unroll
    for (int k = 0; k < 25; k++) {
      const float* wk = ws + OFF_WCE + k * 256 + c;
      acc[k] += wk[0] * v0 + wk[1] * v1 + wk[2] * v2 + wk[3] * v3
              + wk[4] * v4 + wk[5] * v5 + wk[6] * v6 + wk[7] * v7;
    }
  }
#pragma unroll
  for (int k = 0; k < 25; k++) red[g][k][xl] = acc[k];
  __syncthreads();
  for (int item = threadIdx.x; item < 25 * 64; item += 256) {
    int k = item >> 6; int xx = item & 63;
    v2f s = red[0][k][xx] + red[1][k][xx] + red[2][k][xx] + red[3][k][xx];
    float bce = ws[OFF_BCE + k];
    s.x += bce; s.y += bce;
    *(v2f*)(ws + OFF_ENC + ((b * 25 + k) * NH2 + y) * NW2 + 2 * xx) = s;
  }
  // ---- fused o1b: DEC = p0+p1; GATE = sigmoid(p0+p1+bg) ----
  // total NB*26*4096 = 425984 = 512 blocks * 832
  int base = blockIdx.x * 832;
  for (int j = threadIdx.x; j < 832; j += 256) {
    int i = base + j;
    int bb = i / (26 * 4096);
    int r = i - bb * 26 * 4096;
    int o = r >> 12;
    int pix = r & 4095;
    float s = ws[OFF_P1 + (((0 * NB + bb) * 26 + o) << 12) + pix]
            + ws[OFF_P1 + (((1 * NB + bb) * 26 + o) << 12) + pix];
    if (o < 25)
      ws[OFF_DEC + ((bb * 25 + o) << 12) + pix] = s;
    else {
      float z = s + ws[OFF_BG];
      ws[OFF_GATE + (bb << 12) + pix] = 1.f / (1.f + __expf(-z));
    }
  }
}

// raw = dw3x3(ENC)+b + up2(dw3x3(DEC)+b); softmax over 25 -> KB bf16 [b][h][w][tap*4+st]
// grid = B*128*2 (1024): each block = one output row y, 64-pixel x-strip.
// 256 threads = 4 tap-groups x 64 pixels; partial raw -> LDS red[25][64];
// wave 0 does softmax straight from LDS (no 25-register array, no spill).
__global__ __launch_bounds__(256) void o4_kernels(float* ws){
  __shared__ float red[25][64];
  int b = blockIdx.x >> 8;
  int rem = blockIdx.x & 255;
  int y = rem >> 1;
  int xs = (rem & 1) << 6;
  int tg = __builtin_amdgcn_readfirstlane(threadIdx.x >> 6);
  int xl = threadIdx.x & 63;
  int x = xs + xl;
  int h = y >> 1, w = x >> 1;
  const float* enc = ws + OFF_ENC + (b * 25) * NH2 * NW2;
  const float* dec = ws + OFF_DEC + (b * 25) * NH * NW;

  for (int k = tg; k < 25; k += 4) {
    float s = 2.f * ws[OFF_BDW + k];
#pragma unroll
    for (int u = 0; u < 3; u++) {
      int yy = y + u - 1, hh = h + u - 1;
      bool yok = (yy >= 0 && yy < NH2);
      bool hok = (hh >= 0 && hh < NH);
#pragma unroll
      for (int v = 0; v < 3; v++) {
        int xx = x + v - 1, w2 = w + v - 1;
        float wd = ws[OFF_WDW + k * 9 + u * 3 + v];
        if (yok && xx >= 0 && xx < NW2)
          s += enc[(k * NH2 + yy) * NW2 + xx] * wd;
        if (hok && w2 >= 0 && w2 < NW)
          s += dec[(k * NH + hh) * NW + w2] * wd;
      }
    }
    red[k][xl] = s;
  }
  __syncthreads();

  if (threadIdx.x < 64) {
    int t = threadIdx.x;
    int xp = xs + t;
    float m = -1e30f;
#pragma unroll
    for (int k = 0; k < 25; k++) m = fmaxf(m, red[k][t]);
    float sum = 0.f;
#pragma unroll
    for (int k = 0; k < 25; k++) {
      float e = __expf(red[k][t] - m);
      red[k][t] = e;
      sum += e;
    }
    float inv = 1.f / sum;
    int st = ((y & 1) << 1) + (xp & 1);
    int wp = xp >> 1;
    u16* kbu = (u16*)(ws + OFF_KB);
    u16* dst = kbu + ((b * NH + h) * NW + wp) * 100 + st;
#pragma unroll
    for (int k = 0; k < 25; k++) dst[k * 4] = f2bf(red[k][t] * inv);
  }
}

// Channel-major carafe + gate blend, fp32 out.
// grid = B*64*4*2 (2048), block 256 (4 waves), split by output row s.
// Swizzle: xcd = bi&7, slot = bi>>3, s = slot&1, pid = ((slot>>1)<<3)|xcd.
// Phase 1: dy-outer, one acc block for all 4 wu of the wave, 8 unique DET
// columns loaded once per dy (j=i+dx), v_pk_fma_f32 with op_sel k-broadcast.
__global__ __launch_bounds__(256) void o5_final(const void* en, float* ws, float* out){
  __shared__ u16 stag[32][260];
  bool f = ws[OFF_FLAG] != 0.f;
  const u16* det = (const u16*)(ws + OFF_DET);
  const u16* kbu = (const u16*)(ws + OFF_KB);
  const float* gate = ws + OFF_GATE;

  int bi = blockIdx.x;
  int xcd = bi & 7;
  int slot = bi >> 3;
  int s = slot & 1;
  int pid = ((slot >> 1) << 3) | xcd;
  int b = pid >> 8;
  int rem = pid & 255;
  int h = rem >> 2;
  int w0b = (rem & 3) * 16;
  int wave = threadIdx.x >> 6;
  int lane = threadIdx.x & 63;
  int c4 = lane * 4;

  int wu0 = __builtin_amdgcn_readfirstlane(w0b + wave * 4);
  const u16* kp0 = kbu + ((b * NH + h) * NW + wu0) * 100 + s * 2;

  v2f acc[4][2][2];
#pragma unroll
  for (int i = 0; i < 4; i++)
#pragma unroll
    for (int t = 0; t < 2; t++)
#pragma unroll
      for (int p = 0; p < 2; p++) { acc[i][t][p].x = 0.f; acc[i][t][p].y = 0.f; }

#pragma unroll
  for (int dy = 0; dy < 5; dy++) {
    const u16* dp = det + (((b * 68 + h + dy) * 68 + wu0) * NC) + c4;
    u32 wlo[8], whi[8];
#pragma unroll
    for (int j = 0; j < 8; j++) {
      uint2 dv = *(const uint2*)(dp + j * NC);
      wlo[j] = dv.x; whi[j] = dv.y;
    }
#pragma unroll
    for (int i = 0; i < 4; i++) {
#pragma unroll
      for (int dx = 0; dx < 5; dx++) {
        int j = i + dx;
        u32 kk = *(const u32*)(kp0 + i * 100 + (dy * 5 + dx) * 4);  // uniform -> s_load
        v2f kp2, vA, vB;
        kp2.x = __uint_as_float(kk << 16);            // k0 (st s*2)
        kp2.y = __uint_as_float(kk & 0xffff0000u);    // k1 (st s*2+1)
        vA.x = __uint_as_float(wlo[j] << 16);         // c4+0
        vA.y = __uint_as_float(wlo[j] & 0xffff0000u); // c4+1
        vB.x = __uint_as_float(whi[j] << 16);         // c4+2
        vB.y = __uint_as_float(whi[j] & 0xffff0000u); // c4+3
        asm("v_pk_fma_f32 %0, %1, %2, %0 op_sel:[0,0,0] op_sel_hi:[0,1,1]"
            : "+v"(acc[i][0][0]) : "v"(kp2), "v"(vA));
        asm("v_pk_fma_f32 %0, %1, %2, %0 op_sel:[0,0,0] op_sel_hi:[0,1,1]"
            : "+v"(acc[i][0][1]) : "v"(kp2), "v"(vB));
        asm("v_pk_fma_f32 %0, %1, %2, %0 op_sel:[1,0,0] op_sel_hi:[1,1,1]"
            : "+v"(acc[i][1][0]) : "v"(kp2), "v"(vA));
        asm("v_pk_fma_f32 %0, %1, %2, %0 op_sel:[1,0,0] op_sel_hi:[1,1,1]"
            : "+v"(acc[i][1][1]) : "v"(kp2), "v"(vB));
      }
    }
  }

#pragma unroll
  for (int i = 0; i < 4; i++) {
    int xl = (wave * 4 + i) * 2;
#pragma unroll
    for (int t = 0; t < 2; t++) {
      ushort4 pv;
      pv.x = f2bf(acc[i][t][0].x); pv.y = f2bf(acc[i][t][0].y);
      pv.z = f2bf(acc[i][t][1].x); pv.w = f2bf(acc[i][t][1].y);
      *(ushort4*)&stag[xl + t][c4] = pv;
    }
  }
  __syncthreads();

  int xp = threadIdx.x & 31;
  int cb = (threadIdx.x >> 5) * 2;
  int x = w0b * 2 + xp;
  int wpix = w0b + (xp >> 1);
  int y = 2 * h + s;
  float g = gate[(b * NH + h) * NW + wpix];
  float gi = 1.f - g;
#pragma unroll
  for (int pass = 0; pass < 16; pass++) {
    int c = cb + pass * 16;
    u32 rr = *(const u32*)&stag[xp][c];
    float cr0 = bf2f((u16)(rr & 0xffffu));
    float cr1 = bf2f((u16)(rr >> 16));
    int eidx = ((b * NC + c) * NH2 + y) * NW2 + x;
    float e0 = ldin(en, eidx, f);
    float e1 = ldin(en, eidx + NH2 * NW2, f);
    __builtin_nontemporal_store(g * e0 + gi * cr0, &out[eidx]);
    __builtin_nontemporal_store(g * e1 + gi * cr1, &out[eidx + NH2 * NW2]);
  }
}

// ================= naive fallback path (verified round 6) =================

__global__ __launch_bounds__(256) void kA_gate(const void* de, float* ws, int b){
  bool f = ws[OFF_FLAG] != 0.f;
  int idx = blockIdx.x * 256 + threadIdx.x;
  int h = idx >> 6, w = idx & 63;
  float s = ws[OFF_BG];
  for (int c = 0; c < NC; c++)
    s += ldin(de, ((b * NC + c) * NH + h) * NW + w, f) * ws[OFF_WG + c];
  ws[NGATE + idx] = 1.f / (1.f + __expf(-s));
}

__global__ __launch_bounds__(256) void kB_dec(const void* de, float* ws, int b){
  bool f = ws[OFF_FLAG] != 0.f;
  int idx = blockIdx.x * 256 + threadIdx.x;
  int h = idx >> 6, w = idx & 63;
  float acc[25];
#pragma unroll
  for (int k = 0; k < 25; k++) acc[k] = 0.f;
  for (int c = 0; c < NC; c++) {
    float v = ldin(de, ((b * NC + c) * NH + h) * NW + w, f);
#pragma unroll
    for (int k = 0; k < 25; k++) acc[k] += v * ws[OFF_WCD + k * 256 + c];
  }
#pragma unroll
  for (int k = 0; k < 25; k++)
    ws[NDEC + (k * NH + h) * NW + w] = acc[k];
}

__global__ __launch_bounds__(256) void kC_enc(const void* en, float* ws, int b){
  bool f = ws[OFF_FLAG] != 0.f;
  int idx = blockIdx.x * 256 + threadIdx.x;
  int y = idx >> 7, x = idx & 127;
  float acc[25];
#pragma unroll
  for (int k = 0; k < 25; k++) acc[k] = 0.f;
  for (int c = 0; c < NC; c++) {
    float v = ldin(en, ((b * NC + c) * NH2 + y) * NW2 + x, f);
#pragma unroll
    for (int k = 0; k < 25; k++) acc[k] += v * ws[OFF_WCE + k * 256 + c];
  }
#pragma unroll
  for (int k = 0; k < 25; k++)
    ws[NENC + (k * NH2 + y) * NW2 + x] = acc[k] + ws[OFF_BCE + k];
}

__global__ __launch_bounds__(256) void kD_kern(float* ws){
  int idx = blockIdx.x * 256 + threadIdx.x;
  int y = idx >> 7, x = idx & 127;
  int h = y >> 1, w = x >> 1;
  float raw[25];
#pragma unroll
  for (int k = 0; k < 25; k++) {
    float s = 2.f * ws[OFF_BDW + k];
#pragma unroll
    for (int u = 0; u < 3; u++) {
      int yy = y + u - 1, hh = h + u - 1;
#pragma unroll
      for (int v = 0; v < 3; v++) {
        int xx = x + v - 1, ww = w + v - 1;
        float wd = ws[OFF_WDW + k * 9 + u * 3 + v];
        if (yy >= 0 && yy < NH2 && xx >= 0 && xx < NW2)
          s += ws[NENC + (k * NH2 + yy) * NW2 + xx] * wd;
        if (hh >= 0 && hh < NH && ww >= 0 && ww < NW)
          s += ws[NDEC + (k * NH + hh) * NW + ww] * wd;
      }
    }
    raw[k] = s;
  }
  float m = raw[0];
#pragma unroll
  for (int k = 1; k < 25; k++) m = fmaxf(m, raw[k]);
  float sum = 0.f;
#pragma unroll
  for (int k = 0; k < 25; k++) { raw[k] = __expf(raw[k] - m); sum += raw[k]; }
  float inv = 1.f / sum;
  float* dst = ws + NKBF + idx * 25;
#pragma unroll
  for (int k = 0; k < 25; k++) dst[k] = raw[k] * inv;
}

__global__ __launch_bounds__(256) void kE_out(const void* en, const void* de,
    const float* ws, float* out, int b){
  bool f = ws[OFF_FLAG] != 0.f;
  int idx = blockIdx.x * 256 + threadIdx.x;
  int c = idx >> 14;
  int y = (idx >> 7) & 127;
  int x = idx & 127;
  int h = y >> 1, w = x >> 1;
  const float* kb = ws + NKBF + (y * NW2 + x) * 25;
  float acc = 0.f;
#pragma unroll
  for (int dy = 0; dy < 5; dy++) {
    int hh = h + dy - 2;
    if (hh < 0 || hh >= NH) continue;
#pragma unroll
    for (int dx = 0; dx < 5; dx++) {
      int ww = w + dx - 2;
      if (ww < 0 || ww >= NW) continue;
      acc += ldin(de, ((b * NC + c) * NH + hh) * NW + ww, f) * kb[dy * 5 + dx];
    }
  }
  float g = ws[NGATE + h * NW + w];
  float e = ldin(en, ((b * NC + c) * NH2 + y) * NW2 + x, f);
  out[((b * NC + c) * NH2 + y) * NW2 + x] = g * e + (1.f - g) * acc;
}

// resolve input by flat element count (robust to permutation); fallback positional
static const void* find_by_size(void* const* d_in, const int* in_sizes, int n_in,
                                int want, int skip, const void* fb){
  int seen = 0;
  for (int i = 0; i < n_in; i++)
    if (in_sizes[i] == want) {
      if (seen == skip) return d_in[i];
      seen++;
    }
  return fb;
}

extern "C" void kernel_launch(void* const* d_in, const int* in_sizes, int n_in,
                              void* d_out, int out_size, void* d_ws, size_t ws_size,
                              hipStream_t stream) {
  (void)out_size;
  const void* en  = find_by_size(d_in, in_sizes, n_in, 4*256*128*128, 0, d_in[0]);
  const void* de  = find_by_size(d_in, in_sizes, n_in, 4*256*64*64,   0, d_in[1]);
  const void* Wg  = find_by_size(d_in, in_sizes, n_in, 256,           0, d_in[2]);
  const void* bg  = find_by_size(d_in, in_sizes, n_in, 1,             0, d_in[3]);
  const void* Wce = find_by_size(d_in, in_sizes, n_in, 6400,          0, d_in[4]);
  const void* bce = find_by_size(d_in, in_sizes, n_in, 25,            0, d_in[5]);
  const void* Wcd = find_by_size(d_in, in_sizes, n_in, 6400,          1, d_in[6]);
  const void* Wdw = find_by_size(d_in, in_sizes, n_in, 225,           0, d_in[7]);
  const void* bdw = find_by_size(d_in, in_sizes, n_in, 25,            1, d_in[8]);
  float* ws = (float*)d_ws;
  float* out = (float*)d_out;

  hipLaunchKernelGGL(k_prep, dim3(25), dim3(256), 0, stream,
                     de, Wg, bg, Wce, bce, Wcd, Wdw, bdw, ws);

  if (ws_size >= FULL_NEED_BYTES) {
    hipLaunchKernelGGL(o1a_dec_gate, dim3(NB * NH * 2),     dim3(256), 0, stream, de, ws);
    hipLaunchKernelGGL(o3_enc,       dim3(NB * NH2),        dim3(256), 0, stream, en, ws);
    hipLaunchKernelGGL(o4_kernels,   dim3(NB * NH2 * 2),    dim3(256), 0, stream, ws);
    hipLaunchKernelGGL(o2_det,       dim3(NB * 68 * 4),     dim3(256), 0, stream, de, ws);
    hipLaunchKernelGGL(o5_final,     dim3(NB * NH * 4 * 2), dim3(256), 0, stream, en, ws, out);
  } else {
    for (int b = 0; b < NB; b++) {
      hipLaunchKernelGGL(kA_gate, dim3(16),    dim3(256), 0, stream, de, ws, b);
      hipLaunchKernelGGL(kB_dec,  dim3(16),    dim3(256), 0, stream, de, ws, b);
      hipLaunchKernelGGL(kC_enc,  dim3(64),    dim3(256), 0, stream, en, ws, b);
      hipLaunchKernelGGL(kD_kern, dim3(64),    dim3(256), 0, stream, ws);
      hipLaunchKernelGGL(kE_out,  dim3(16384), dim3(256), 0, stream, en, de, ws, out, b);
    }
  }
}

// Round 7
// 238.170 us; speedup vs baseline: 1.5975x; 1.0073x over previous
//
#include <hip/hip_runtime.h>

// FADE-Lite round 14: r13 with the nontemporal-store compile fix.
// __builtin_nontemporal_store requires a clang ext_vector, not HIP's float4
// class -> use v4f (ext_vector_type(4)) in o5 phase 2 / ldin4.
// Content otherwise identical to r13: (a) o3 reverted to proven r11 structure
// (grid 1024, 4x64ch groups, scalar x8-unrolled loads) + fused o1b tail;
// (b) o5 phase 2 remapped to x-quads: dwordx4 en loads + nontemporal dwordx4
// out stores (VMEM instr / 4, same 128B coalescing), gate staged in LDS.
//
// out = gate*en + (1-gate)*CARAFE(de, softmax_k(dw3x3(conv1x1(en,Wce))+up2(dw3x3(conv1x1(de,Wcd)))))
// B=4, C=256, H=64, W=64. Inputs fp32 (runtime-detected), output fp32.

typedef unsigned short u16;
typedef unsigned int u32;
typedef float v2f __attribute__((ext_vector_type(2)));
typedef float v4f __attribute__((ext_vector_type(4)));

#define NB 4
#define NC 256
#define NH 64
#define NW 64
#define NH2 128
#define NW2 128

// fp32 weights in ws (shared by both paths)
#define OFF_WG   0
#define OFF_BG   256
#define OFF_WCE  272
#define OFF_BCE  6672
#define OFF_WCD  6704
#define OFF_WDW  13104
#define OFF_BDW  13330
#define OFF_FLAG 13356    // 1.0f = fp32 inputs, 0.0f = bf16 inputs

// ---- optimized (full-batch) layout, floats ----
#define OFF_GATE 16384    // 4*4096 fp32                    -> 32768
#define OFF_KB   32768    // 4*4096*100 u16 (819200 fl)     -> 851968
#define OFF_ENC  851968   // 4*25*16384 fp32                -> 2490368
#define OFF_DEC  2490368  // 4*25*4096 fp32                 -> 2899968
#define OFF_DET  851968   // 4*68*68*256 u16, aliases dead ENC+DEC after o4 -> 3219456
#define OFF_P1   3219456  // o1a partials: 2*4*26*4096 fl (dedicated) -> 4071424
#define FULL_NEED_BYTES 16285696ull

// ---- naive (per-batch) layout, floats ----
#define NGATE 16384
#define NDEC  20480
#define NENC  122880
#define NKBF  532480      // -> end 942080 (3.77 MB)

__device__ __forceinline__ float bf2f(u16 u){ return __uint_as_float(((u32)u) << 16); }
__device__ __forceinline__ u16 f2bf(float f){
  u32 x = __float_as_uint(f);
  return (u16)((x + 0x7fffu + ((x >> 16) & 1u)) >> 16);  // RNE (finite)
}
__device__ __forceinline__ float ldin(const void* p, int i, bool f32){
  return f32 ? ((const float*)p)[i] : bf2f(((const u16*)p)[i]);
}
// quad load: elements i..i+3 (i multiple of 4)
__device__ __forceinline__ v4f ldin4(const void* p, int i, bool f32){
  v4f r;
  if (f32) {
    r = *(const v4f*)((const float*)p + i);
  } else {
    ushort4 u = *(const ushort4*)((const u16*)p + i);
    r.x = bf2f(u.x); r.y = bf2f(u.y); r.z = bf2f(u.z); r.w = bf2f(u.w);
  }
  return r;
}

// k_prep with fused dtype detect: every block votes on 512 samples of `de`
// (identical data -> identical result); block 0 publishes the flag for later
// kernels. bf16 exp in [0x70,0x82] nearly always; fp32 low-u16s ~7% hit.
__global__ __launch_bounds__(256) void k_prep(const void* de_raw,
    const void* Wg, const void* bg, const void* Wce, const void* bce,
    const void* Wcd, const void* Wdw, const void* bdw, float* ws){
  __shared__ int cnt;
  if (threadIdx.x == 0) cnt = 0;
  __syncthreads();
  int c = 0;
#pragma unroll
  for (int s = 0; s < 2; s++) {
    int i = (threadIdx.x + s * 256) * 2;
    u16 u = ((const u16*)de_raw)[i];
    int e = (u >> 7) & 0xff;
    if (e >= 0x70 && e <= 0x82) c++;
  }
  atomicAdd(&cnt, c);
  __syncthreads();
  bool f = cnt < 256;
  if (blockIdx.x == 0 && threadIdx.x == 0) ws[OFF_FLAG] = f ? 1.0f : 0.0f;
  int i = threadIdx.x + blockIdx.x * 256;
  if (i < 6400) {
    ws[OFF_WCE + i] = ldin(Wce, i, f);
    ws[OFF_WCD + i] = ldin(Wcd, i, f);
    if (i < 256) ws[OFF_WG + i] = ldin(Wg, i, f);
    if (i < 1)   ws[OFF_BG + i] = ldin(bg, i, f);
    if (i < 25)  ws[OFF_BCE + i] = ldin(bce, i, f);
    if (i < 225) ws[OFF_WDW + i] = ldin(Wdw, i, f);
    if (i < 25)  ws[OFF_BDW + i] = ldin(bdw, i, f);
  }
}

// ================= optimized path =================

// o1a: partial DEC/GATE over a 128-channel chunk.
// grid = B*64*2 (512): b = bi>>7, rem&127 -> h = rem>>1, chunk = rem&1.
// block 256 = 4 waves; wave g covers channels chunk*128 + g*32 .. +31.
// Partials (raw, no bias/sigmoid) -> OFF_P1[(chunk*NB+b)*26+o][h][w].
__global__ __launch_bounds__(256) void o1a_dec_gate(const void* de, float* ws){
  __shared__ float red[4][26][64];
  bool f = ws[OFF_FLAG] != 0.f;
  int b = blockIdx.x >> 7;
  int rem = blockIdx.x & 127;
  int h = rem >> 1;
  int chunk = rem & 1;
  int g = threadIdx.x >> 6;
  int w = threadIdx.x & 63;
  int c0 = __builtin_amdgcn_readfirstlane(chunk * 128 + g * 32);
  float acc[26];
#pragma unroll
  for (int o = 0; o < 26; o++) acc[o] = 0.f;
  int idx = ((b * NC + c0) * NH + h) * NW + w;
  for (int ci = 0; ci < 32; ci += 8) {
    float v0 = ldin(de, idx,            f);
    float v1 = ldin(de, idx + 1 * 4096, f);
    float v2 = ldin(de, idx + 2 * 4096, f);
    float v3 = ldin(de, idx + 3 * 4096, f);
    float v4 = ldin(de, idx + 4 * 4096, f);
    float v5 = ldin(de, idx + 5 * 4096, f);
    float v6 = ldin(de, idx + 6 * 4096, f);
    float v7 = ldin(de, idx + 7 * 4096, f);
    idx += 8 * 4096;
    int c = c0 + ci;
    acc[25] += ws[OFF_WG + c] * v0 + ws[OFF_WG + c + 1] * v1
             + ws[OFF_WG + c + 2] * v2 + ws[OFF_WG + c + 3] * v3
             + ws[OFF_WG + c + 4] * v4 + ws[OFF_WG + c + 5] * v5
             + ws[OFF_WG + c + 6] * v6 + ws[OFF_WG + c + 7] * v7;
#pragma unroll
    for (int k = 0; k < 25; k++) {
      const float* wk = ws + OFF_WCD + k * 256 + c;
      acc[k] += wk[0] * v0 + wk[1] * v1 + wk[2] * v2 + wk[3] * v3
              + wk[4] * v4 + wk[5] * v5 + wk[6] * v6 + wk[7] * v7;
    }
  }
#pragma unroll
  for (int o = 0; o < 26; o++) red[g][o][w] = acc[o];
  __syncthreads();
  for (int item = threadIdx.x; item < 26 * 64; item += 256) {
    int o = item >> 6; int ww = item & 63;
    float s = red[0][o][ww] + red[1][o][ww] + red[2][o][ww] + red[3][o][ww];
    ws[OFF_P1 + (((chunk * NB + b) * 26 + o) << 12) + (h << 6) + ww] = s;
  }
}

// DET[b][p][q][c] = de[b][c][p-2][q-2] (0 outside), bf16. Runs AFTER o4 (aliases ENC+DEC).
// grid = B*68*4 (1088): b = bi/272, r = bi%272, p = r>>2, c-chunk = (r&3)*64.
// Coalesced de reads (lanes across w) -> LDS transpose tile[64][65] ->
// coalesced DET writes (lanes across c).
__global__ __launch_bounds__(256) void o2_det(const void* de, float* ws){
  __shared__ float tile[64][65];
  bool f = ws[OFF_FLAG] != 0.f;
  u16* det = (u16*)(ws + OFF_DET);
  int b = blockIdx.x / 272;
  int r = blockIdx.x % 272;
  int p = r >> 2;
  int c0 = (r & 3) << 6;
  int h = p - 2;
  bool hv = (h >= 0 && h < NH);
  for (int item = threadIdx.x; item < 64 * 64; item += 256) {
    int cl = item >> 6, w = item & 63;
    float v = hv ? ldin(de, ((b * NC + c0 + cl) * NH + h) * NW + w, f) : 0.f;
    tile[w][cl] = v;
  }
  __syncthreads();
  u16* dst = det + ((b * 68 + p) * 68) * NC + c0;
  for (int item = threadIdx.x; item < 68 * 64; item += 256) {
    int q = item >> 6, cl = item & 63;
    int w = q - 2;
    float v = (w >= 0 && w < NW) ? tile[w][cl] : 0.f;
    dst[q * NC + cl] = f2bf(v);
  }
}

// ENC = conv1x1(en, W_ce)+b_ce.  (r11 structure, proven)
// grid = B*128*2 (1024): b = bi>>8, rem&255 -> y = rem>>1, xs = (rem&1)*64.
// block 256 = 4 waves; wave g covers channels g*64..+63, lanes = 64 x.
// Channel loop unrolled x8 with independent temps -> 8 loads in flight.
// Tail: fused o1b reduce (DEC/GATE from P1) - 416 elements per block.
__global__ __launch_bounds__(256) void o3_enc(const void* en, float* ws){
  __shared__ float red[4][25][64];
  bool f = ws[OFF_FLAG] != 0.f;
  int b = blockIdx.x >> 8;
  int rem = blockIdx.x & 255;
  int y = rem >> 1;
  int xs = (rem & 1) << 6;
  int g = threadIdx.x >> 6;
  int xl = threadIdx.x & 63;
  int c0 = __builtin_amdgcn_readfirstlane(g * 64);
  float acc[25];
#pragma unroll
  for (int k = 0; k < 25; k++) acc[k] = 0.f;
  int idx = ((b * NC + c0) * NH2 + y) * NW2 + xs + xl;
  for (int ci = 0; ci < 64; ci += 8) {
    float v0 = ldin(en, idx,             f);
    float v1 = ldin(en, idx + 1 * 16384, f);
    float v2 = ldin(en, idx + 2 * 16384, f);
    float v3 = ldin(en, idx + 3 * 16384, f);
    float v4 = ldin(en, idx + 4 * 16384, f);
    float v5 = ldin(en, idx + 5 * 16384, f);
    float v6 = ldin(en, idx + 6 * 16384, f);
    float v7 = ldin(en, idx + 7 * 16384, f);
    idx += 8 * 16384;
    int c = c0 + ci;
#pragma unroll
    for (int k = 0; k < 25; k++) {
      const float* wk = ws + OFF_WCE + k * 256 + c;
      acc[k] += wk[0] * v0 + wk[1] * v1 + wk[2] * v2 + wk[3] * v3
              + wk[4] * v4 + wk[5] * v5 + wk[6] * v6 + wk[7] * v7;
    }
  }
#pragma unroll
  for (int k = 0; k < 25; k++) red[g][k][xl] = acc[k];
  __syncthreads();
  for (int item = threadIdx.x; item < 25 * 64; item += 256) {
    int k = item >> 6; int xx = item & 63;
    float s = red[0][k][xx] + red[1][k][xx] + red[2][k][xx] + red[3][k][xx]
            + ws[OFF_BCE + k];
    ws[OFF_ENC + ((b * 25 + k) * NH2 + y) * NW2 + xs + xx] = s;
  }
  // ---- fused o1b: DEC = p0+p1; GATE = sigmoid(p0+p1+bg) ----
  // total NB*26*4096 = 425984 = 1024 blocks * 416
  int base = blockIdx.x * 416;
  for (int j = threadIdx.x; j < 416; j += 256) {
    int i = base + j;
    int bb = i / (26 * 4096);
    int r = i - bb * 26 * 4096;
    int o = r >> 12;
    int pix = r & 4095;
    float s = ws[OFF_P1 + (((0 * NB + bb) * 26 + o) << 12) + pix]
            + ws[OFF_P1 + (((1 * NB + bb) * 26 + o) << 12) + pix];
    if (o < 25)
      ws[OFF_DEC + ((bb * 25 + o) << 12) + pix] = s;
    else {
      float z = s + ws[OFF_BG];
      ws[OFF_GATE + (bb << 12) + pix] = 1.f / (1.f + __expf(-z));
    }
  }
}

// raw = dw3x3(ENC)+b + up2(dw3x3(DEC)+b); softmax over 25 -> KB bf16 [b][h][w][tap*4+st]
// grid = B*128*2 (1024): each block = one output row y, 64-pixel x-strip.
// 256 threads = 4 tap-groups x 64 pixels; partial raw -> LDS red[25][64];
// wave 0 does softmax straight from LDS (no 25-register array, no spill).
__global__ __launch_bounds__(256) void o4_kernels(float* ws){
  __shared__ float red[25][64];
  int b = blockIdx.x >> 8;
  int rem = blockIdx.x & 255;
  int y = rem >> 1;
  int xs = (rem & 1) << 6;
  int tg = __builtin_amdgcn_readfirstlane(threadIdx.x >> 6);
  int xl = threadIdx.x & 63;
  int x = xs + xl;
  int h = y >> 1, w = x >> 1;
  const float* enc = ws + OFF_ENC + (b * 25) * NH2 * NW2;
  const float* dec = ws + OFF_DEC + (b * 25) * NH * NW;

  for (int k = tg; k < 25; k += 4) {
    float s = 2.f * ws[OFF_BDW + k];
#pragma unroll
    for (int u = 0; u < 3; u++) {
      int yy = y + u - 1, hh = h + u - 1;
      bool yok = (yy >= 0 && yy < NH2);
      bool hok = (hh >= 0 && hh < NH);
#pragma unroll
      for (int v = 0; v < 3; v++) {
        int xx = x + v - 1, w2 = w + v - 1;
        float wd = ws[OFF_WDW + k * 9 + u * 3 + v];
        if (yok && xx >= 0 && xx < NW2)
          s += enc[(k * NH2 + yy) * NW2 + xx] * wd;
        if (hok && w2 >= 0 && w2 < NW)
          s += dec[(k * NH + hh) * NW + w2] * wd;
      }
    }
    red[k][xl] = s;
  }
  __syncthreads();

  if (threadIdx.x < 64) {
    int t = threadIdx.x;
    int xp = xs + t;
    float m = -1e30f;
#pragma unroll
    for (int k = 0; k < 25; k++) m = fmaxf(m, red[k][t]);
    float sum = 0.f;
#pragma unroll
    for (int k = 0; k < 25; k++) {
      float e = __expf(red[k][t] - m);
      red[k][t] = e;
      sum += e;
    }
    float inv = 1.f / sum;
    int st = ((y & 1) << 1) + (xp & 1);
    int wp = xp >> 1;
    u16* kbu = (u16*)(ws + OFF_KB);
    u16* dst = kbu + ((b * NH + h) * NW + wp) * 100 + st;
#pragma unroll
    for (int k = 0; k < 25; k++) dst[k * 4] = f2bf(red[k][t] * inv);
  }
}

// Channel-major carafe + gate blend, fp32 out.
// grid = B*64*4*2 (2048), block 256 (4 waves), split by output row s.
// Swizzle: xcd = bi&7, slot = bi>>3, s = slot&1, pid = ((slot>>1)<<3)|xcd.
// Phase 1: dy-outer, one acc block for all 4 wu of the wave, 8 unique DET
// columns loaded once per dy (j=i+dx), v_pk_fma_f32 with op_sel k-broadcast.
// Phase 2: x-quad remap - dwordx4 en loads + nontemporal dwordx4 stores
// (VMEM instr / 4, same 128B segments), gate staged in LDS.
__global__ __launch_bounds__(256) void o5_final(const void* en, float* ws, float* out){
  __shared__ u16 stag[32][260];
  __shared__ float gsh[16];
  bool f = ws[OFF_FLAG] != 0.f;
  const u16* det = (const u16*)(ws + OFF_DET);
  const u16* kbu = (const u16*)(ws + OFF_KB);
  const float* gate = ws + OFF_GATE;

  int bi = blockIdx.x;
  int xcd = bi & 7;
  int slot = bi >> 3;
  int s = slot & 1;
  int pid = ((slot >> 1) << 3) | xcd;
  int b = pid >> 8;
  int rem = pid & 255;
  int h = rem >> 2;
  int w0b = (rem & 3) * 16;
  int wave = threadIdx.x >> 6;
  int lane = threadIdx.x & 63;
  int c4 = lane * 4;

  if (threadIdx.x < 16)
    gsh[threadIdx.x] = gate[(b * NH + h) * NW + w0b + threadIdx.x];

  int wu0 = __builtin_amdgcn_readfirstlane(w0b + wave * 4);
  const u16* kp0 = kbu + ((b * NH + h) * NW + wu0) * 100 + s * 2;

  v2f acc[4][2][2];
#pragma unroll
  for (int i = 0; i < 4; i++)
#pragma unroll
    for (int t = 0; t < 2; t++)
#pragma unroll
      for (int p = 0; p < 2; p++) { acc[i][t][p].x = 0.f; acc[i][t][p].y = 0.f; }

#pragma unroll
  for (int dy = 0; dy < 5; dy++) {
    const u16* dp = det + (((b * 68 + h + dy) * 68 + wu0) * NC) + c4;
    u32 wlo[8], whi[8];
#pragma unroll
    for (int j = 0; j < 8; j++) {
      uint2 dv = *(const uint2*)(dp + j * NC);
      wlo[j] = dv.x; whi[j] = dv.y;
    }
#pragma unroll
    for (int i = 0; i < 4; i++) {
#pragma unroll
      for (int dx = 0; dx < 5; dx++) {
        int j = i + dx;
        u32 kk = *(const u32*)(kp0 + i * 100 + (dy * 5 + dx) * 4);  // uniform -> s_load
        v2f kp2, vA, vB;
        kp2.x = __uint_as_float(kk << 16);            // k0 (st s*2)
        kp2.y = __uint_as_float(kk & 0xffff0000u);    // k1 (st s*2+1)
        vA.x = __uint_as_float(wlo[j] << 16);         // c4+0
        vA.y = __uint_as_float(wlo[j] & 0xffff0000u); // c4+1
        vB.x = __uint_as_float(whi[j] << 16);         // c4+2
        vB.y = __uint_as_float(whi[j] & 0xffff0000u); // c4+3
        asm("v_pk_fma_f32 %0, %1, %2, %0 op_sel:[0,0,0] op_sel_hi:[0,1,1]"
            : "+v"(acc[i][0][0]) : "v"(kp2), "v"(vA));
        asm("v_pk_fma_f32 %0, %1, %2, %0 op_sel:[0,0,0] op_sel_hi:[0,1,1]"
            : "+v"(acc[i][0][1]) : "v"(kp2), "v"(vB));
        asm("v_pk_fma_f32 %0, %1, %2, %0 op_sel:[1,0,0] op_sel_hi:[1,1,1]"
            : "+v"(acc[i][1][0]) : "v"(kp2), "v"(vA));
        asm("v_pk_fma_f32 %0, %1, %2, %0 op_sel:[1,0,0] op_sel_hi:[1,1,1]"
            : "+v"(acc[i][1][1]) : "v"(kp2), "v"(vB));
      }
    }
  }

#pragma unroll
  for (int i = 0; i < 4; i++) {
    int xl = (wave * 4 + i) * 2;
#pragma unroll
    for (int t = 0; t < 2; t++) {
      ushort4 pv;
      pv.x = f2bf(acc[i][t][0].x); pv.y = f2bf(acc[i][t][0].y);
      pv.z = f2bf(acc[i][t][1].x); pv.w = f2bf(acc[i][t][1].y);
      *(ushort4*)&stag[xl + t][c4] = pv;
    }
  }
  __syncthreads();

  // phase 2: thread -> x-quad (xq) + 32-channel slice per pass
  int xq = threadIdx.x & 7;        // x = x0..x0+3
  int cc = threadIdx.x >> 3;       // 0..31
  int x0 = w0b * 2 + xq * 4;
  int xls = xq * 4;                // local x in stag
  float g0 = gsh[xq * 2], g1 = gsh[xq * 2 + 1];
  float gi0 = 1.f - g0, gi1 = 1.f - g1;
  int y = 2 * h + s;
#pragma unroll
  for (int pass = 0; pass < 8; pass++) {
    int c = cc + pass * 32;
    float cr0 = bf2f(stag[xls + 0][c]);
    float cr1 = bf2f(stag[xls + 1][c]);
    float cr2 = bf2f(stag[xls + 2][c]);
    float cr3 = bf2f(stag[xls + 3][c]);
    int eidx = ((b * NC + c) * NH2 + y) * NW2 + x0;
    v4f e = ldin4(en, eidx, f);
    v4f o;
    o.x = g0 * e.x + gi0 * cr0;
    o.y = g0 * e.y + gi0 * cr1;
    o.z = g1 * e.z + gi1 * cr2;
    o.w = g1 * e.w + gi1 * cr3;
    __builtin_nontemporal_store(o, (v4f*)&out[eidx]);
  }
}

// ================= naive fallback path (verified round 6) =================

__global__ __launch_bounds__(256) void kA_gate(const void* de, float* ws, int b){
  bool f = ws[OFF_FLAG] != 0.f;
  int idx = blockIdx.x * 256 + threadIdx.x;
  int h = idx >> 6, w = idx & 63;
  float s = ws[OFF_BG];
  for (int c = 0; c < NC; c++)
    s += ldin(de, ((b * NC + c) * NH + h) * NW + w, f) * ws[OFF_WG + c];
  ws[NGATE + idx] = 1.f / (1.f + __expf(-s));
}

__global__ __launch_bounds__(256) void kB_dec(const void* de, float* ws, int b){
  bool f = ws[OFF_FLAG] != 0.f;
  int idx = blockIdx.x * 256 + threadIdx.x;
  int h = idx >> 6, w = idx & 63;
  float acc[25];
#pragma unroll
  for (int k = 0; k < 25; k++) acc[k] = 0.f;
  for (int c = 0; c < NC; c++) {
    float v = ldin(de, ((b * NC + c) * NH + h) * NW + w, f);
#pragma unroll
    for (int k = 0; k < 25; k++) acc[k] += v * ws[OFF_WCD + k * 256 + c];
  }
#pragma unroll
  for (int k = 0; k < 25; k++)
    ws[NDEC + (k * NH + h) * NW + w] = acc[k];
}

__global__ __launch_bounds__(256) void kC_enc(const void* en, float* ws, int b){
  bool f = ws[OFF_FLAG] != 0.f;
  int idx = blockIdx.x * 256 + threadIdx.x;
  int y = idx >> 7, x = idx & 127;
  float acc[25];
#pragma unroll
  for (int k = 0; k < 25; k++) acc[k] = 0.f;
  for (int c = 0; c < NC; c++) {
    float v = ldin(en, ((b * NC + c) * NH2 + y) * NW2 + x, f);
#pragma unroll
    for (int k = 0; k < 25; k++) acc[k] += v * ws[OFF_WCE + k * 256 + c];
  }
#pragma unroll
  for (int k = 0; k < 25; k++)
    ws[NENC + (k * NH2 + y) * NW2 + x] = acc[k] + ws[OFF_BCE + k];
}

__global__ __launch_bounds__(256) void kD_kern(float* ws){
  int idx = blockIdx.x * 256 + threadIdx.x;
  int y = idx >> 7, x = idx & 127;
  int h = y >> 1, w = x >> 1;
  float raw[25];
#pragma unroll
  for (int k = 0; k < 25; k++) {
    float s = 2.f * ws[OFF_BDW + k];
#pragma unroll
    for (int u = 0; u < 3; u++) {
      int yy = y + u - 1, hh = h + u - 1;
#pragma unroll
      for (int v = 0; v < 3; v++) {
        int xx = x + v - 1, ww = w + v - 1;
        float wd = ws[OFF_WDW + k * 9 + u * 3 + v];
        if (yy >= 0 && yy < NH2 && xx >= 0 && xx < NW2)
          s += ws[NENC + (k * NH2 + yy) * NW2 + xx] * wd;
        if (hh >= 0 && hh < NH && ww >= 0 && ww < NW)
          s += ws[NDEC + (k * NH + hh) * NW + ww] * wd;
      }
    }
    raw[k] = s;
  }
  float m = raw[0];
#pragma unroll
  for (int k = 1; k < 25; k++) m = fmaxf(m, raw[k]);
  float sum = 0.f;
#pragma unroll
  for (int k = 0; k < 25; k++) { raw[k] = __expf(raw[k] - m); sum += raw[k]; }
  float inv = 1.f / sum;
  float* dst = ws + NKBF + idx * 25;
#pragma unroll
  for (int k = 0; k < 25; k++) dst[k] = raw[k] * inv;
}

__global__ __launch_bounds__(256) void kE_out(const void* en, const void* de,
    const float* ws, float* out, int b){
  bool f = ws[OFF_FLAG] != 0.f;
  int idx = blockIdx.x * 256 + threadIdx.x;
  int c = idx >> 14;
  int y = (idx >> 7) & 127;
  int x = idx & 127;
  int h = y >> 1, w = x >> 1;
  const float* kb = ws + NKBF + (y * NW2 + x) * 25;
  float acc = 0.f;
#pragma unroll
  for (int dy = 0; dy < 5; dy++) {
    int hh = h + dy - 2;
    if (hh < 0 || hh >= NH) continue;
#pragma unroll
    for (int dx = 0; dx < 5; dx++) {
      int ww = w + dx - 2;
      if (ww < 0 || ww >= NW) continue;
      acc += ldin(de, ((b * NC + c) * NH + hh) * NW + ww, f) * kb[dy * 5 + dx];
    }
  }
  float g = ws[NGATE + h * NW + w];
  float e = ldin(en, ((b * NC + c) * NH2 + y) * NW2 + x, f);
  out[((b * NC + c) * NH2 + y) * NW2 + x] = g * e + (1.f - g) * acc;
}

// resolve input by flat element count (robust to permutation); fallback positional
static const void* find_by_size(void* const* d_in, const int* in_sizes, int n_in,
                                int want, int skip, const void* fb){
  int seen = 0;
  for (int i = 0; i < n_in; i++)
    if (in_sizes[i] == want) {
      if (seen == skip) return d_in[i];
      seen++;
    }
  return fb;
}

extern "C" void kernel_launch(void* const* d_in, const int* in_sizes, int n_in,
                              void* d_out, int out_size, void* d_ws, size_t ws_size,
                              hipStream_t stream) {
  (void)out_size;
  const void* en  = find_by_size(d_in, in_sizes, n_in, 4*256*128*128, 0, d_in[0]);
  const void* de  = find_by_size(d_in, in_sizes, n_in, 4*256*64*64,   0, d_in[1]);
  const void* Wg  = find_by_size(d_in, in_sizes, n_in, 256,           0, d_in[2]);
  const void* bg  = find_by_size(d_in, in_sizes, n_in, 1,             0, d_in[3]);
  const void* Wce = find_by_size(d_in, in_sizes, n_in, 6400,          0, d_in[4]);
  const void* bce = find_by_size(d_in, in_sizes, n_in, 25,            0, d_in[5]);
  const void* Wcd = find_by_size(d_in, in_sizes, n_in, 6400,          1, d_in[6]);
  const void* Wdw = find_by_size(d_in, in_sizes, n_in, 225,           0, d_in[7]);
  const void* bdw = find_by_size(d_in, in_sizes, n_in, 25,            1, d_in[8]);
  float* ws = (float*)d_ws;
  float* out = (float*)d_out;

  hipLaunchKernelGGL(k_prep, dim3(25), dim3(256), 0, stream,
                     de, Wg, bg, Wce, bce, Wcd, Wdw, bdw, ws);

  if (ws_size >= FULL_NEED_BYTES) {
    hipLaunchKernelGGL(o1a_dec_gate, dim3(NB * NH * 2),     dim3(256), 0, stream, de, ws);
    hipLaunchKernelGGL(o3_enc,       dim3(NB * NH2 * 2),    dim3(256), 0, stream, en, ws);
    hipLaunchKernelGGL(o4_kernels,   dim3(NB * NH2 * 2),    dim3(256), 0, stream, ws);
    hipLaunchKernelGGL(o2_det,       dim3(NB * 68 * 4),     dim3(256), 0, stream, de, ws);
    hipLaunchKernelGGL(o5_final,     dim3(NB * NH * 4 * 2), dim3(256), 0, stream, en, ws, out);
  } else {
    for (int b = 0; b < NB; b++) {
      hipLaunchKernelGGL(kA_gate, dim3(16),    dim3(256), 0, stream, de, ws, b);
      hipLaunchKernelGGL(kB_dec,  dim3(16),    dim3(256), 0, stream, de, ws, b);
      hipLaunchKernelGGL(kC_enc,  dim3(64),    dim3(256), 0, stream, en, ws, b);
      hipLaunchKernelGGL(kD_kern, dim3(64),    dim3(256), 0, stream, ws);
      hipLaunchKernelGGL(kE_out,  dim3(16384), dim3(256), 0, stream, en, de, ws, out, b);
    }
  }
}